// Round 1
// baseline (1739.444 us; speedup 1.0000x reference)
//
#include <hip/hip_runtime.h>
#include <hip/hip_bf16.h>
#include <math.h>

#define NNODES 50000
#define NEDGES 800000
#define DMODEL 128
#define NHEADS 8
#define HDIM 16
#define QK_SCALE 0.25f  // 1/sqrt(16)

// ---------------------------------------------------------------------------
// helpers
// ---------------------------------------------------------------------------
__device__ __forceinline__ void atomicMaxFloat(float* addr, float val) {
    // sign-split trick: positive floats ordered as ints, negative reversed as uints.
    // segmax must be initialized to -inf (0xFF800000) for this to be correct.
    if (val >= 0.0f) {
        atomicMax((int*)addr, __float_as_int(val));
    } else {
        atomicMin((unsigned int*)addr, __float_as_uint(val));
    }
}

__global__ __launch_bounds__(256) void fill_neginf(float* p, int n) {
    int i = blockIdx.x * 256 + threadIdx.x;
    if (i < n) p[i] = -__builtin_inff();
}

__global__ __launch_bounds__(256) void invert_kernel(float* p, int n) {
    int i = blockIdx.x * 256 + threadIdx.x;
    if (i < n) {
        float d = p[i];
        p[i] = (d > 0.0f) ? (1.0f / d) : 0.0f;
    }
}

// ---------------------------------------------------------------------------
// C[M,N] = A[M,128] @ W[128,N] + bias[N]      (K fixed at 128)
// 64x64 tile, 256 threads, 4x4 micro-tile, BK=32
// ---------------------------------------------------------------------------
#define TM 64
#define TN 64
#define TK 32
__global__ __launch_bounds__(256) void gemm128(const float* __restrict__ A,
                                               const float* __restrict__ W,
                                               const float* __restrict__ bias,
                                               float* __restrict__ C,
                                               int M, int N) {
    __shared__ float As[TK][TM + 4];  // [k][m], row stride 68 floats = 272B (16B aligned)
    __shared__ float Bs[TK][TN + 4];  // [k][n]

    int tid = threadIdx.x;
    int bm = blockIdx.x * TM;
    int bn = blockIdx.y * TN;
    int ty = tid >> 4;   // 0..15 -> rows ty*4..ty*4+3
    int tx = tid & 15;   // 0..15 -> cols tx*4..tx*4+3

    float acc[4][4] = {};

    for (int k0 = 0; k0 < 128; k0 += TK) {
        // A tile: 64 rows x 32 cols = 512 float4, 2 per thread
        #pragma unroll
        for (int i = 0; i < 2; ++i) {
            int idx = tid + i * 256;       // 0..511
            int row = idx >> 3;            // 8 float4 per row
            int c4  = idx & 7;
            int grow = bm + row;
            if (grow >= M) grow = M - 1;   // clamp; stores are guarded
            float4 v = *(const float4*)&A[(size_t)grow * 128 + k0 + c4 * 4];
            As[c4 * 4 + 0][row] = v.x;
            As[c4 * 4 + 1][row] = v.y;
            As[c4 * 4 + 2][row] = v.z;
            As[c4 * 4 + 3][row] = v.w;
        }
        // B tile: 32 rows x 64 cols = 512 float4, 2 per thread
        #pragma unroll
        for (int i = 0; i < 2; ++i) {
            int idx = tid + i * 256;
            int row = idx >> 4;            // 16 float4 per row
            int c4  = idx & 15;
            float4 v = *(const float4*)&W[(size_t)(k0 + row) * N + bn + c4 * 4];
            *(float4*)&Bs[row][c4 * 4] = v;
        }
        __syncthreads();

        #pragma unroll
        for (int kk = 0; kk < TK; ++kk) {
            float4 a4 = *(const float4*)&As[kk][ty * 4];
            float4 b4 = *(const float4*)&Bs[kk][tx * 4];
            float av[4] = {a4.x, a4.y, a4.z, a4.w};
            float bv[4] = {b4.x, b4.y, b4.z, b4.w};
            #pragma unroll
            for (int i = 0; i < 4; ++i)
                #pragma unroll
                for (int j = 0; j < 4; ++j)
                    acc[i][j] += av[i] * bv[j];
        }
        __syncthreads();
    }

    float4 bvec = *(const float4*)&bias[bn + tx * 4];
    float bb[4] = {bvec.x, bvec.y, bvec.z, bvec.w};
    #pragma unroll
    for (int i = 0; i < 4; ++i) {
        int gr = bm + ty * 4 + i;
        if (gr < M) {
            float4 o;
            o.x = acc[i][0] + bb[0];
            o.y = acc[i][1] + bb[1];
            o.z = acc[i][2] + bb[2];
            o.w = acc[i][3] + bb[3];
            *(float4*)&C[(size_t)gr * N + bn + tx * 4] = o;
        }
    }
}

// ---------------------------------------------------------------------------
// edge scores: 8 lanes per edge (one head each)
// score[e,h] = (Q[row[e],h,:] . K[col[e],h,:]) * SCALE + ef[e,:] . We[:,h] + be[h]
// also atomic segment-max into segmax[row,h]
// ---------------------------------------------------------------------------
__global__ __launch_bounds__(256) void edge_scores(const float* __restrict__ Q,
                                                   const float* __restrict__ Km,
                                                   const float* __restrict__ EF,
                                                   const int* __restrict__ row,
                                                   const int* __restrict__ col,
                                                   const float* __restrict__ We,
                                                   const float* __restrict__ be,
                                                   float* __restrict__ scores,
                                                   float* __restrict__ segmax) {
    __shared__ float sWe[128 * 8];
    __shared__ float sbe[8];
    for (int i = threadIdx.x; i < 1024; i += 256) sWe[i] = We[i];
    if (threadIdx.x < 8) sbe[threadIdx.x] = be[threadIdx.x];
    __syncthreads();

    int g = blockIdx.x * 256 + threadIdx.x;   // < NEDGES*8 = 6.4M
    int e = g >> 3;
    int h = g & 7;
    if (e >= NEDGES) return;

    int r = row[e];
    int c = col[e];

    const float4* q = (const float4*)(Q + (size_t)r * 128 + h * 16);
    const float4* k = (const float4*)(Km + (size_t)c * 128 + h * 16);
    float dot = 0.0f;
    #pragma unroll
    for (int i = 0; i < 4; ++i) {
        float4 qv = q[i];
        float4 kv = k[i];
        dot += qv.x * kv.x + qv.y * kv.y + qv.z * kv.z + qv.w * kv.w;
    }

    float bias = sbe[h];
    const float4* ef = (const float4*)(EF + (size_t)e * 128);
    #pragma unroll 4
    for (int d4 = 0; d4 < 32; ++d4) {
        float4 v = ef[d4];
        bias += v.x * sWe[(d4 * 4 + 0) * 8 + h]
              + v.y * sWe[(d4 * 4 + 1) * 8 + h]
              + v.z * sWe[(d4 * 4 + 2) * 8 + h]
              + v.w * sWe[(d4 * 4 + 3) * 8 + h];
    }

    float s = dot * QK_SCALE + bias;
    scores[g] = s;
    atomicMaxFloat(&segmax[r * 8 + h], s);
}

// ---------------------------------------------------------------------------
// ex = exp(score - segmax[row]);  denom[row,h] += ex  (scores overwritten)
// ---------------------------------------------------------------------------
__global__ __launch_bounds__(256) void exp_denom(float* __restrict__ scores,
                                                 const float* __restrict__ segmax,
                                                 const int* __restrict__ row,
                                                 float* __restrict__ denom) {
    int g = blockIdx.x * 256 + threadIdx.x;
    int e = g >> 3;
    int h = g & 7;
    if (e >= NEDGES) return;
    int r = row[e];
    float x = __expf(scores[g] - segmax[r * 8 + h]);
    scores[g] = x;
    atomicAdd(&denom[r * 8 + h], x);
}

// ---------------------------------------------------------------------------
// out_agg[row,:] += (ex/denom[row]) * V[col,:]   — one thread per (edge, 4 dims)
// ---------------------------------------------------------------------------
__global__ __launch_bounds__(256) void aggregate(const float* __restrict__ ex,
                                                 const float* __restrict__ inv_denom,
                                                 const float* __restrict__ V,
                                                 const int* __restrict__ row,
                                                 const int* __restrict__ col,
                                                 float* __restrict__ agg) {
    int g = blockIdx.x * 256 + threadIdx.x;   // < NEDGES*32 = 25.6M
    int e  = g >> 5;
    int d4 = g & 31;
    int h  = d4 >> 2;
    if (e >= NEDGES) return;
    int r = row[e];
    int c = col[e];
    float att = ex[e * 8 + h] * inv_denom[r * 8 + h];
    float4 v = *(const float4*)&V[(size_t)c * 128 + d4 * 4];
    float* dst = &agg[(size_t)r * 128 + d4 * 4];
    atomicAdd(dst + 0, att * v.x);
    atomicAdd(dst + 1, att * v.y);
    atomicAdd(dst + 2, att * v.z);
    atomicAdd(dst + 3, att * v.w);
}

// ---------------------------------------------------------------------------
extern "C" void kernel_launch(void* const* d_in, const int* in_sizes, int n_in,
                              void* d_out, int out_size, void* d_ws, size_t ws_size,
                              hipStream_t stream) {
    const float* node = (const float*)d_in[0];
    const int*   ei   = (const int*)d_in[1];
    const float* ef   = (const float*)d_in[2];
    const float* Wq   = (const float*)d_in[3];
    const float* bq   = (const float*)d_in[4];
    const float* Wk   = (const float*)d_in[5];
    const float* bk   = (const float*)d_in[6];
    const float* Wv   = (const float*)d_in[7];
    const float* bv   = (const float*)d_in[8];
    const float* We   = (const float*)d_in[9];
    const float* be   = (const float*)d_in[10];
    const float* Wo   = (const float*)d_in[11];
    const float* bo   = (const float*)d_in[12];
    float* out = (float*)d_out;

    const int* row = ei;
    const int* col = ei + NEDGES;

    // workspace layout (floats)
    float* ws   = (float*)d_ws;
    float* Q    = ws;                                  // NNODES*128
    float* Km   = Q    + (size_t)NNODES * 128;         // NNODES*128
    float* V    = Km   + (size_t)NNODES * 128;         // NNODES*128
    float* sc   = V    + (size_t)NNODES * 128;         // NEDGES*8
    float* smax = sc   + (size_t)NEDGES * 8;           // NNODES*8
    float* den  = smax + (size_t)NNODES * 8;           // NNODES*8
    float* agg  = den  + (size_t)NNODES * 8;           // NNODES*128

    // per-launch init (graph-replay safe: poison-proof)
    hipMemsetAsync(den, 0, (size_t)NNODES * 8 * sizeof(float), stream);
    hipMemsetAsync(agg, 0, (size_t)NNODES * 128 * sizeof(float), stream);
    fill_neginf<<<(NNODES * 8 + 255) / 256, 256, 0, stream>>>(smax, NNODES * 8);

    dim3 gq((NNODES + TM - 1) / TM, DMODEL / TN);
    gemm128<<<gq, 256, 0, stream>>>(node, Wq, bq, Q,  NNODES, DMODEL);
    gemm128<<<gq, 256, 0, stream>>>(node, Wk, bk, Km, NNODES, DMODEL);
    gemm128<<<gq, 256, 0, stream>>>(node, Wv, bv, V,  NNODES, DMODEL);

    edge_scores<<<NEDGES * 8 / 256, 256, 0, stream>>>(Q, Km, ef, row, col, We, be, sc, smax);
    exp_denom<<<NEDGES * 8 / 256, 256, 0, stream>>>(sc, smax, row, den);
    invert_kernel<<<(NNODES * 8 + 255) / 256, 256, 0, stream>>>(den, NNODES * 8);
    aggregate<<<NEDGES * 32 / 256, 256, 0, stream>>>(sc, den, V, row, col, agg);

    gemm128<<<gq, 256, 0, stream>>>(agg, Wo, bo, out, NNODES, DMODEL);
}

// Round 2
// 710.800 us; speedup vs baseline: 2.4472x; 2.4472x over previous
//
#include <hip/hip_runtime.h>
#include <hip/hip_bf16.h>
#include <math.h>

#define NNODES 50000
#define NEDGES 800000
#define DMODEL 128
#define QK_SCALE 0.25f  // 1/sqrt(16)

// ---------------------------------------------------------------------------
// C[M,N] = A[M,128] @ W[128,N] + bias[N]      (K fixed at 128)
// 64x64 tile, 256 threads, 4x4 micro-tile, BK=32
// ---------------------------------------------------------------------------
#define TM 64
#define TN 64
#define TK 32
__global__ __launch_bounds__(256) void gemm128(const float* __restrict__ A,
                                               const float* __restrict__ W,
                                               const float* __restrict__ bias,
                                               float* __restrict__ C,
                                               int M, int N) {
    __shared__ float As[TK][TM + 4];
    __shared__ float Bs[TK][TN + 4];

    int tid = threadIdx.x;
    int bm = blockIdx.x * TM;
    int bn = blockIdx.y * TN;
    int ty = tid >> 4;
    int tx = tid & 15;

    float acc[4][4] = {};

    for (int k0 = 0; k0 < 128; k0 += TK) {
        #pragma unroll
        for (int i = 0; i < 2; ++i) {
            int idx = tid + i * 256;
            int row = idx >> 3;
            int c4  = idx & 7;
            int grow = bm + row;
            if (grow >= M) grow = M - 1;
            float4 v = *(const float4*)&A[(size_t)grow * 128 + k0 + c4 * 4];
            As[c4 * 4 + 0][row] = v.x;
            As[c4 * 4 + 1][row] = v.y;
            As[c4 * 4 + 2][row] = v.z;
            As[c4 * 4 + 3][row] = v.w;
        }
        #pragma unroll
        for (int i = 0; i < 2; ++i) {
            int idx = tid + i * 256;
            int row = idx >> 4;
            int c4  = idx & 15;
            float4 v = *(const float4*)&W[(size_t)(k0 + row) * N + bn + c4 * 4];
            *(float4*)&Bs[row][c4 * 4] = v;
        }
        __syncthreads();

        #pragma unroll
        for (int kk = 0; kk < TK; ++kk) {
            float4 a4 = *(const float4*)&As[kk][ty * 4];
            float4 b4 = *(const float4*)&Bs[kk][tx * 4];
            float av[4] = {a4.x, a4.y, a4.z, a4.w};
            float bv[4] = {b4.x, b4.y, b4.z, b4.w};
            #pragma unroll
            for (int i = 0; i < 4; ++i)
                #pragma unroll
                for (int j = 0; j < 4; ++j)
                    acc[i][j] += av[i] * bv[j];
        }
        __syncthreads();
    }

    float4 bvec = *(const float4*)&bias[bn + tx * 4];
    float bb[4] = {bvec.x, bvec.y, bvec.z, bvec.w};
    #pragma unroll
    for (int i = 0; i < 4; ++i) {
        int gr = bm + ty * 4 + i;
        if (gr < M) {
            float4 o;
            o.x = acc[i][0] + bb[0];
            o.y = acc[i][1] + bb[1];
            o.z = acc[i][2] + bb[2];
            o.w = acc[i][3] + bb[3];
            *(float4*)&C[(size_t)gr * N + bn + tx * 4] = o;
        }
    }
}

// ---------------------------------------------------------------------------
// CSR build: histogram -> scan -> scatter
// ---------------------------------------------------------------------------
__global__ __launch_bounds__(256) void hist_kernel(const int* __restrict__ row,
                                                   int* __restrict__ cnt) {
    int e = blockIdx.x * 256 + threadIdx.x;
    if (e < NEDGES) atomicAdd(&cnt[row[e]], 1);
}

__global__ __launch_bounds__(1024) void scan_kernel(const int* __restrict__ cnt,
                                                    int* __restrict__ offs,
                                                    int* __restrict__ cursor) {
    __shared__ int psum[1024];
    int tid = threadIdx.x;
    const int CH = (NNODES + 1023) / 1024;  // 49
    int base = tid * CH;
    int s = 0;
    for (int i = 0; i < CH; ++i) {
        int idx = base + i;
        if (idx < NNODES) s += cnt[idx];
    }
    psum[tid] = s;
    __syncthreads();
    for (int off = 1; off < 1024; off <<= 1) {
        int v = (tid >= off) ? psum[tid - off] : 0;
        __syncthreads();
        psum[tid] += v;
        __syncthreads();
    }
    int running = (tid == 0) ? 0 : psum[tid - 1];
    for (int i = 0; i < CH; ++i) {
        int idx = base + i;
        if (idx < NNODES) {
            offs[idx] = running;
            cursor[idx] = running;
            running += cnt[idx];
        }
    }
    if (tid == 0) offs[NNODES] = NEDGES;
}

__global__ __launch_bounds__(256) void scatter_kernel(const int* __restrict__ row,
                                                      int* __restrict__ cursor,
                                                      int* __restrict__ perm) {
    int e = blockIdx.x * 256 + threadIdx.x;
    if (e < NEDGES) {
        int pos = atomicAdd(&cursor[row[e]], 1);
        perm[pos] = e;
    }
}

// ---------------------------------------------------------------------------
// edge scores: 8 lanes per edge (one head each), no atomics
// ---------------------------------------------------------------------------
__global__ __launch_bounds__(256) void edge_scores(const float* __restrict__ Q,
                                                   const float* __restrict__ Km,
                                                   const float* __restrict__ EF,
                                                   const int* __restrict__ row,
                                                   const int* __restrict__ col,
                                                   const float* __restrict__ We,
                                                   const float* __restrict__ be,
                                                   float* __restrict__ scores) {
    __shared__ float sWe[128 * 8];
    __shared__ float sbe[8];
    for (int i = threadIdx.x; i < 1024; i += 256) sWe[i] = We[i];
    if (threadIdx.x < 8) sbe[threadIdx.x] = be[threadIdx.x];
    __syncthreads();

    int g = blockIdx.x * 256 + threadIdx.x;   // < NEDGES*8
    int e = g >> 3;
    int h = g & 7;
    if (e >= NEDGES) return;

    int r = row[e];
    int c = col[e];

    const float4* q = (const float4*)(Q + (size_t)r * 128 + h * 16);
    const float4* k = (const float4*)(Km + (size_t)c * 128 + h * 16);
    float dot = 0.0f;
    #pragma unroll
    for (int i = 0; i < 4; ++i) {
        float4 qv = q[i];
        float4 kv = k[i];
        dot += qv.x * kv.x + qv.y * kv.y + qv.z * kv.z + qv.w * kv.w;
    }

    float bias = sbe[h];
    const float4* ef = (const float4*)(EF + (size_t)e * 128);
    #pragma unroll 4
    for (int d4 = 0; d4 < 32; ++d4) {
        float4 v = ef[d4];
        bias += v.x * sWe[(d4 * 4 + 0) * 8 + h]
              + v.y * sWe[(d4 * 4 + 1) * 8 + h]
              + v.z * sWe[(d4 * 4 + 2) * 8 + h]
              + v.w * sWe[(d4 * 4 + 3) * 8 + h];
    }

    scores[g] = dot * QK_SCALE + bias;
}

// ---------------------------------------------------------------------------
// fused segment softmax + aggregation, one wave per destination node.
// lane l handles output dims {2l, 2l+1}; its head is l/8.
// pass 1: per-head max; pass 2: exp-sum + weighted V accumulation; normalize.
// No atomics.
// ---------------------------------------------------------------------------
__global__ __launch_bounds__(256) void softmax_agg(const float* __restrict__ scores,
                                                   const float* __restrict__ V,
                                                   const int* __restrict__ col,
                                                   const int* __restrict__ perm,
                                                   const int* __restrict__ offs,
                                                   float* __restrict__ agg) {
    int node = blockIdx.x * 4 + (threadIdx.x >> 6);
    if (node >= NNODES) return;
    int lane = threadIdx.x & 63;
    int h = lane >> 3;
    int start = offs[node];
    int end = offs[node + 1];

    float m = -3.0e38f;
    for (int i = start; i < end; ++i) {
        int e = perm[i];
        m = fmaxf(m, scores[e * 8 + h]);
    }

    float sum = 0.0f;
    float ax = 0.0f, ay = 0.0f;
    for (int i = start; i < end; ++i) {
        int e = perm[i];
        float w = __expf(scores[e * 8 + h] - m);
        sum += w;
        int c = col[e];
        float2 v = *(const float2*)&V[(size_t)c * 128 + lane * 2];
        ax += w * v.x;
        ay += w * v.y;
    }

    float inv = (sum > 0.0f) ? (1.0f / sum) : 0.0f;
    float2 o = make_float2(ax * inv, ay * inv);
    *(float2*)&agg[(size_t)node * 128 + lane * 2] = o;
}

// ---------------------------------------------------------------------------
extern "C" void kernel_launch(void* const* d_in, const int* in_sizes, int n_in,
                              void* d_out, int out_size, void* d_ws, size_t ws_size,
                              hipStream_t stream) {
    const float* node = (const float*)d_in[0];
    const int*   ei   = (const int*)d_in[1];
    const float* ef   = (const float*)d_in[2];
    const float* Wq   = (const float*)d_in[3];
    const float* bq   = (const float*)d_in[4];
    const float* Wk   = (const float*)d_in[5];
    const float* bk   = (const float*)d_in[6];
    const float* Wv   = (const float*)d_in[7];
    const float* bv   = (const float*)d_in[8];
    const float* We   = (const float*)d_in[9];
    const float* be   = (const float*)d_in[10];
    const float* Wo   = (const float*)d_in[11];
    const float* bo   = (const float*)d_in[12];
    float* out = (float*)d_out;

    const int* row = ei;
    const int* col = ei + NEDGES;

    // workspace layout
    float* ws   = (float*)d_ws;
    float* Q    = ws;                                  // NNODES*128
    float* Km   = Q    + (size_t)NNODES * 128;         // NNODES*128
    float* V    = Km   + (size_t)NNODES * 128;         // NNODES*128
    float* sc   = V    + (size_t)NNODES * 128;         // NEDGES*8
    int*   cnt    = (int*)(sc + (size_t)NEDGES * 8);   // NNODES
    int*   offs   = cnt + NNODES;                      // NNODES+1
    int*   cursor = offs + NNODES + 1;                 // NNODES
    int*   perm   = cursor + NNODES;                   // NEDGES
    float* agg  = Q;  // alias: Q dead after edge_scores

    // CSR build (rebuilt every launch; deterministic work)
    hipMemsetAsync(cnt, 0, (size_t)NNODES * sizeof(int), stream);
    hist_kernel<<<(NEDGES + 255) / 256, 256, 0, stream>>>(row, cnt);
    scan_kernel<<<1, 1024, 0, stream>>>(cnt, offs, cursor);
    scatter_kernel<<<(NEDGES + 255) / 256, 256, 0, stream>>>(row, cursor, perm);

    dim3 gq((NNODES + TM - 1) / TM, DMODEL / TN);
    gemm128<<<gq, 256, 0, stream>>>(node, Wq, bq, Q,  NNODES, DMODEL);
    gemm128<<<gq, 256, 0, stream>>>(node, Wk, bk, Km, NNODES, DMODEL);
    gemm128<<<gq, 256, 0, stream>>>(node, Wv, bv, V,  NNODES, DMODEL);

    edge_scores<<<NEDGES * 8 / 256, 256, 0, stream>>>(Q, Km, ef, row, col, We, be, sc);

    softmax_agg<<<(NNODES + 3) / 4, 256, 0, stream>>>(sc, V, col, perm, offs, agg);

    gemm128<<<gq, 256, 0, stream>>>(agg, Wo, bo, out, NNODES, DMODEL);
}

// Round 3
// 616.421 us; speedup vs baseline: 2.8218x; 1.1531x over previous
//
#include <hip/hip_runtime.h>
#include <hip/hip_bf16.h>
#include <math.h>

#define NNODES 50000
#define NEDGES 800000
#define DMODEL 128
#define QK_SCALE 0.25f  // 1/sqrt(16)

// ---------------------------------------------------------------------------
// C[M,N] = A[M,128] @ W[128,N] + bias[N]      (K fixed at 128)
// ---------------------------------------------------------------------------
#define TM 64
#define TN 64
#define TK 32
__global__ __launch_bounds__(256) void gemm128(const float* __restrict__ A,
                                               const float* __restrict__ W,
                                               const float* __restrict__ bias,
                                               float* __restrict__ C,
                                               int M, int N) {
    __shared__ float As[TK][TM + 4];
    __shared__ float Bs[TK][TN + 4];

    int tid = threadIdx.x;
    int bm = blockIdx.x * TM;
    int bn = blockIdx.y * TN;
    int ty = tid >> 4;
    int tx = tid & 15;

    float acc[4][4] = {};

    for (int k0 = 0; k0 < 128; k0 += TK) {
        #pragma unroll
        for (int i = 0; i < 2; ++i) {
            int idx = tid + i * 256;
            int row = idx >> 3;
            int c4  = idx & 7;
            int grow = bm + row;
            if (grow >= M) grow = M - 1;
            float4 v = *(const float4*)&A[(size_t)grow * 128 + k0 + c4 * 4];
            As[c4 * 4 + 0][row] = v.x;
            As[c4 * 4 + 1][row] = v.y;
            As[c4 * 4 + 2][row] = v.z;
            As[c4 * 4 + 3][row] = v.w;
        }
        #pragma unroll
        for (int i = 0; i < 2; ++i) {
            int idx = tid + i * 256;
            int row = idx >> 4;
            int c4  = idx & 15;
            float4 v = *(const float4*)&W[(size_t)(k0 + row) * N + bn + c4 * 4];
            *(float4*)&Bs[row][c4 * 4] = v;
        }
        __syncthreads();

        #pragma unroll
        for (int kk = 0; kk < TK; ++kk) {
            float4 a4 = *(const float4*)&As[kk][ty * 4];
            float4 b4 = *(const float4*)&Bs[kk][tx * 4];
            float av[4] = {a4.x, a4.y, a4.z, a4.w};
            float bv[4] = {b4.x, b4.y, b4.z, b4.w};
            #pragma unroll
            for (int i = 0; i < 4; ++i)
                #pragma unroll
                for (int j = 0; j < 4; ++j)
                    acc[i][j] += av[i] * bv[j];
        }
        __syncthreads();
    }

    float4 bvec = *(const float4*)&bias[bn + tx * 4];
    float bb[4] = {bvec.x, bvec.y, bvec.z, bvec.w};
    #pragma unroll
    for (int i = 0; i < 4; ++i) {
        int gr = bm + ty * 4 + i;
        if (gr < M) {
            float4 o;
            o.x = acc[i][0] + bb[0];
            o.y = acc[i][1] + bb[1];
            o.z = acc[i][2] + bb[2];
            o.w = acc[i][3] + bb[3];
            *(float4*)&C[(size_t)gr * N + bn + tx * 4] = o;
        }
    }
}

// ---------------------------------------------------------------------------
// CSR build: histogram -> scan -> scatter (also emits rank & permuted col)
// ---------------------------------------------------------------------------
__global__ __launch_bounds__(256) void hist_kernel(const int* __restrict__ row,
                                                   int* __restrict__ cnt) {
    int e = blockIdx.x * 256 + threadIdx.x;
    if (e < NEDGES) atomicAdd(&cnt[row[e]], 1);
}

__global__ __launch_bounds__(1024) void scan_kernel(const int* __restrict__ cnt,
                                                    int* __restrict__ offs,
                                                    int* __restrict__ cursor) {
    __shared__ int psum[1024];
    int tid = threadIdx.x;
    const int CH = (NNODES + 1023) / 1024;  // 49
    int base = tid * CH;
    int s = 0;
    for (int i = 0; i < CH; ++i) {
        int idx = base + i;
        if (idx < NNODES) s += cnt[idx];
    }
    psum[tid] = s;
    __syncthreads();
    for (int off = 1; off < 1024; off <<= 1) {
        int v = (tid >= off) ? psum[tid - off] : 0;
        __syncthreads();
        psum[tid] += v;
        __syncthreads();
    }
    int running = (tid == 0) ? 0 : psum[tid - 1];
    for (int i = 0; i < CH; ++i) {
        int idx = base + i;
        if (idx < NNODES) {
            offs[idx] = running;
            cursor[idx] = running;
            running += cnt[idx];
        }
    }
    if (tid == 0) offs[NNODES] = NEDGES;
}

__global__ __launch_bounds__(256) void scatter_kernel(const int* __restrict__ row,
                                                      const int* __restrict__ col,
                                                      int* __restrict__ cursor,
                                                      int* __restrict__ rank,
                                                      int* __restrict__ col_perm) {
    int e = blockIdx.x * 256 + threadIdx.x;
    if (e < NEDGES) {
        int pos = atomicAdd(&cursor[row[e]], 1);
        rank[e] = pos;
        col_perm[pos] = col[e];
    }
}

// ---------------------------------------------------------------------------
// edge scores: 8 lanes per edge (one head each); writes scores in CSR order
// ---------------------------------------------------------------------------
__global__ __launch_bounds__(256) void edge_scores(const float* __restrict__ Q,
                                                   const float* __restrict__ Km,
                                                   const float* __restrict__ EF,
                                                   const int* __restrict__ row,
                                                   const int* __restrict__ col,
                                                   const int* __restrict__ rank,
                                                   const float* __restrict__ We,
                                                   const float* __restrict__ be,
                                                   float* __restrict__ scores_perm) {
    __shared__ float sWe[128 * 8];
    __shared__ float sbe[8];
    for (int i = threadIdx.x; i < 1024; i += 256) sWe[i] = We[i];
    if (threadIdx.x < 8) sbe[threadIdx.x] = be[threadIdx.x];
    __syncthreads();

    int g = blockIdx.x * 256 + threadIdx.x;   // < NEDGES*8
    int e = g >> 3;
    int h = g & 7;
    if (e >= NEDGES) return;

    int r = row[e];
    int c = col[e];
    int pos = rank[e];

    const float4* q = (const float4*)(Q + (size_t)r * 128 + h * 16);
    const float4* k = (const float4*)(Km + (size_t)c * 128 + h * 16);
    float dot = 0.0f;
    #pragma unroll
    for (int i = 0; i < 4; ++i) {
        float4 qv = q[i];
        float4 kv = k[i];
        dot += qv.x * kv.x + qv.y * kv.y + qv.z * kv.z + qv.w * kv.w;
    }

    float bias = sbe[h];
    const float4* ef = (const float4*)(EF + (size_t)e * 128);
    #pragma unroll 4
    for (int d4 = 0; d4 < 32; ++d4) {
        float4 v = ef[d4];
        bias += v.x * sWe[(d4 * 4 + 0) * 8 + h]
              + v.y * sWe[(d4 * 4 + 1) * 8 + h]
              + v.z * sWe[(d4 * 4 + 2) * 8 + h]
              + v.w * sWe[(d4 * 4 + 3) * 8 + h];
    }

    scores_perm[(size_t)pos * 8 + h] = dot * QK_SCALE + bias;
}

// ---------------------------------------------------------------------------
// fused single-pass (online) segment softmax + aggregation.
// one wave per destination node; lane l owns dims {2l,2l+1}, head = l/8.
// scores & col are read CONTIGUOUSLY (CSR order); only V is gathered.
// ---------------------------------------------------------------------------
__global__ __launch_bounds__(256) void softmax_agg(const float* __restrict__ scores_perm,
                                                   const float* __restrict__ V,
                                                   const int* __restrict__ col_perm,
                                                   const int* __restrict__ offs,
                                                   float* __restrict__ agg) {
    int node = blockIdx.x * 4 + (threadIdx.x >> 6);
    if (node >= NNODES) return;
    int lane = threadIdx.x & 63;
    int h = lane >> 3;
    int start = offs[node];
    int end = offs[node + 1];

    float m = -3.0e38f;
    float sum = 0.0f;
    float ax = 0.0f, ay = 0.0f;

    #pragma unroll 2
    for (int i = start; i < end; ++i) {
        float s = scores_perm[(size_t)i * 8 + h];
        int c = col_perm[i];
        float2 v = *(const float2*)&V[(size_t)c * 128 + lane * 2];
        float m_new = fmaxf(m, s);
        float corr = __expf(m - m_new);        // 0 on first iter, 1 when no new max
        float w = __expf(s - m_new);
        sum = sum * corr + w;
        ax = ax * corr + w * v.x;
        ay = ay * corr + w * v.y;
        m = m_new;
    }

    float inv = (sum > 0.0f) ? (1.0f / sum) : 0.0f;
    float2 o = make_float2(ax * inv, ay * inv);
    *(float2*)&agg[(size_t)node * 128 + lane * 2] = o;
}

// ---------------------------------------------------------------------------
extern "C" void kernel_launch(void* const* d_in, const int* in_sizes, int n_in,
                              void* d_out, int out_size, void* d_ws, size_t ws_size,
                              hipStream_t stream) {
    const float* node = (const float*)d_in[0];
    const int*   ei   = (const int*)d_in[1];
    const float* ef   = (const float*)d_in[2];
    const float* Wq   = (const float*)d_in[3];
    const float* bq   = (const float*)d_in[4];
    const float* Wk   = (const float*)d_in[5];
    const float* bk   = (const float*)d_in[6];
    const float* Wv   = (const float*)d_in[7];
    const float* bv   = (const float*)d_in[8];
    const float* We   = (const float*)d_in[9];
    const float* be   = (const float*)d_in[10];
    const float* Wo   = (const float*)d_in[11];
    const float* bo   = (const float*)d_in[12];
    float* out = (float*)d_out;

    const int* row = ei;
    const int* col = ei + NEDGES;

    // workspace layout
    float* ws   = (float*)d_ws;
    float* Q    = ws;                                  // NNODES*128
    float* Km   = Q    + (size_t)NNODES * 128;         // NNODES*128
    float* V    = Km   + (size_t)NNODES * 128;         // NNODES*128
    float* sc   = V    + (size_t)NNODES * 128;         // NEDGES*8 (CSR order)
    int*   cnt      = (int*)(sc + (size_t)NEDGES * 8); // NNODES
    int*   offs     = cnt + NNODES;                    // NNODES+1
    int*   cursor   = offs + NNODES + 1;               // NNODES
    int*   rank     = cursor + NNODES;                 // NEDGES
    int*   col_perm = rank + NEDGES;                   // NEDGES
    float* agg  = Q;  // alias: Q dead after edge_scores

    // CSR build (rebuilt every launch)
    hipMemsetAsync(cnt, 0, (size_t)NNODES * sizeof(int), stream);
    hist_kernel<<<(NEDGES + 255) / 256, 256, 0, stream>>>(row, cnt);
    scan_kernel<<<1, 1024, 0, stream>>>(cnt, offs, cursor);
    scatter_kernel<<<(NEDGES + 255) / 256, 256, 0, stream>>>(row, col, cursor, rank, col_perm);

    dim3 gq((NNODES + TM - 1) / TM, DMODEL / TN);
    gemm128<<<gq, 256, 0, stream>>>(node, Wq, bq, Q,  NNODES, DMODEL);
    gemm128<<<gq, 256, 0, stream>>>(node, Wk, bk, Km, NNODES, DMODEL);
    gemm128<<<gq, 256, 0, stream>>>(node, Wv, bv, V,  NNODES, DMODEL);

    edge_scores<<<NEDGES * 8 / 256, 256, 0, stream>>>(Q, Km, ef, row, col, rank, We, be, sc);

    softmax_agg<<<(NNODES + 3) / 4, 256, 0, stream>>>(sc, V, col_perm, offs, agg);

    gemm128<<<gq, 256, 0, stream>>>(agg, Wo, bo, out, NNODES, DMODEL);
}

// Round 4
// 564.288 us; speedup vs baseline: 3.0825x; 1.0924x over previous
//
#include <hip/hip_runtime.h>
#include <hip/hip_bf16.h>
#include <math.h>

#define NNODES 50000
#define NEDGES 800000
#define DMODEL 128
#define QK_SCALE 0.25f  // 1/sqrt(16)

typedef float fvec4 __attribute__((ext_vector_type(4)));

// ---------------------------------------------------------------------------
// C[M,N] = A[M,128] @ W[128,N] + bias[N]      (K fixed at 128)
// ---------------------------------------------------------------------------
#define TM 64
#define TN 64
#define TK 32
__global__ __launch_bounds__(256) void gemm128(const float* __restrict__ A,
                                               const float* __restrict__ W,
                                               const float* __restrict__ bias,
                                               float* __restrict__ C,
                                               int M, int N) {
    __shared__ float As[TK][TM + 4];
    __shared__ float Bs[TK][TN + 4];

    int tid = threadIdx.x;
    int bm = blockIdx.x * TM;
    int bn = blockIdx.y * TN;
    int ty = tid >> 4;
    int tx = tid & 15;

    float acc[4][4] = {};

    for (int k0 = 0; k0 < 128; k0 += TK) {
        #pragma unroll
        for (int i = 0; i < 2; ++i) {
            int idx = tid + i * 256;
            int row = idx >> 3;
            int c4  = idx & 7;
            int grow = bm + row;
            if (grow >= M) grow = M - 1;
            float4 v = *(const float4*)&A[(size_t)grow * 128 + k0 + c4 * 4];
            As[c4 * 4 + 0][row] = v.x;
            As[c4 * 4 + 1][row] = v.y;
            As[c4 * 4 + 2][row] = v.z;
            As[c4 * 4 + 3][row] = v.w;
        }
        #pragma unroll
        for (int i = 0; i < 2; ++i) {
            int idx = tid + i * 256;
            int row = idx >> 4;
            int c4  = idx & 15;
            float4 v = *(const float4*)&W[(size_t)(k0 + row) * N + bn + c4 * 4];
            *(float4*)&Bs[row][c4 * 4] = v;
        }
        __syncthreads();

        #pragma unroll
        for (int kk = 0; kk < TK; ++kk) {
            float4 a4 = *(const float4*)&As[kk][ty * 4];
            float4 b4 = *(const float4*)&Bs[kk][tx * 4];
            float av[4] = {a4.x, a4.y, a4.z, a4.w};
            float bv[4] = {b4.x, b4.y, b4.z, b4.w};
            #pragma unroll
            for (int i = 0; i < 4; ++i)
                #pragma unroll
                for (int j = 0; j < 4; ++j)
                    acc[i][j] += av[i] * bv[j];
        }
        __syncthreads();
    }

    float4 bvec = *(const float4*)&bias[bn + tx * 4];
    float bb[4] = {bvec.x, bvec.y, bvec.z, bvec.w};
    #pragma unroll
    for (int i = 0; i < 4; ++i) {
        int gr = bm + ty * 4 + i;
        if (gr < M) {
            float4 o;
            o.x = acc[i][0] + bb[0];
            o.y = acc[i][1] + bb[1];
            o.z = acc[i][2] + bb[2];
            o.w = acc[i][3] + bb[3];
            *(float4*)&C[(size_t)gr * N + bn + tx * 4] = o;
        }
    }
}

// ---------------------------------------------------------------------------
// CSR build: histogram -> scan -> scatter (emits rank & permuted col)
// ---------------------------------------------------------------------------
__global__ __launch_bounds__(256) void hist_kernel(const int* __restrict__ row,
                                                   int* __restrict__ cnt) {
    int e = blockIdx.x * 256 + threadIdx.x;
    if (e < NEDGES) atomicAdd(&cnt[row[e]], 1);
}

__global__ __launch_bounds__(1024) void scan_kernel(const int* __restrict__ cnt,
                                                    int* __restrict__ offs,
                                                    int* __restrict__ cursor) {
    __shared__ int psum[1024];
    int tid = threadIdx.x;
    const int CH = (NNODES + 1023) / 1024;  // 49
    int base = tid * CH;
    int s = 0;
    for (int i = 0; i < CH; ++i) {
        int idx = base + i;
        if (idx < NNODES) s += cnt[idx];
    }
    psum[tid] = s;
    __syncthreads();
    for (int off = 1; off < 1024; off <<= 1) {
        int v = (tid >= off) ? psum[tid - off] : 0;
        __syncthreads();
        psum[tid] += v;
        __syncthreads();
    }
    int running = (tid == 0) ? 0 : psum[tid - 1];
    for (int i = 0; i < CH; ++i) {
        int idx = base + i;
        if (idx < NNODES) {
            offs[idx] = running;
            cursor[idx] = running;
            running += cnt[idx];
        }
    }
    if (tid == 0) offs[NNODES] = NEDGES;
}

__global__ __launch_bounds__(256) void scatter_kernel(const int* __restrict__ row,
                                                      const int* __restrict__ col,
                                                      int* __restrict__ cursor,
                                                      int* __restrict__ rank,
                                                      int* __restrict__ col_perm) {
    int e = blockIdx.x * 256 + threadIdx.x;
    if (e < NEDGES) {
        int pos = atomicAdd(&cursor[row[e]], 1);
        rank[e] = pos;
        col_perm[pos] = col[e];
    }
}

// ---------------------------------------------------------------------------
// ebias[pos,h] = ef[e,:] . We[:,h] + be[h]   written in CSR order (pos=rank[e])
// 8 lanes per edge; lane s streams float4s d4 = s, s+8, s+16, s+24 (coalesced
// 128B runs, nontemporal). We staged [h][d] in LDS -> 8-way broadcast b128
// reads, conflict-free. Butterfly reduce over the 8 lanes.
// ---------------------------------------------------------------------------
__global__ __launch_bounds__(256) void ef_bias_kernel(const float* __restrict__ EF,
                                                      const int* __restrict__ rank,
                                                      const float* __restrict__ We,
                                                      const float* __restrict__ be,
                                                      float* __restrict__ ebias) {
    __shared__ float sWe[8][128];   // [h][d]
    __shared__ float sbe[8];
    for (int i = threadIdx.x; i < 1024; i += 256) {
        int d = i >> 3, h = i & 7;
        sWe[h][d] = We[i];          // We is [d][h] row-major: We[d*8+h]
    }
    if (threadIdx.x < 8) sbe[threadIdx.x] = be[threadIdx.x];
    __syncthreads();

    int g = blockIdx.x * 256 + threadIdx.x;   // NEDGES*8 threads
    int e = g >> 3;
    int s = g & 7;
    if (e >= NEDGES) return;

    const fvec4* efv = (const fvec4*)(EF + (size_t)e * 128);
    float acc[8] = {0.f, 0.f, 0.f, 0.f, 0.f, 0.f, 0.f, 0.f};
    #pragma unroll
    for (int i = 0; i < 4; ++i) {
        int d4 = s + 8 * i;
        fvec4 v = __builtin_nontemporal_load(&efv[d4]);
        #pragma unroll
        for (int h = 0; h < 8; ++h) {
            fvec4 w = *(const fvec4*)&sWe[h][d4 * 4];
            acc[h] += v.x * w.x + v.y * w.y + v.z * w.z + v.w * w.w;
        }
    }

    #pragma unroll
    for (int off = 1; off < 8; off <<= 1)
        #pragma unroll
        for (int h = 0; h < 8; ++h)
            acc[h] += __shfl_xor(acc[h], off);

    int pos = rank[e];
    ebias[(size_t)pos * 8 + s] = acc[s] + sbe[s];
}

// ---------------------------------------------------------------------------
// fully fused QK^T + online segment softmax + PV aggregation.
// one wave per destination node; lane l owns dims {2l,2l+1}, head = l>>3.
// Q row lives in registers (read ONCE per node). Per edge (CSR order):
// K/V float2 gathers (512B/wave coalesced), 3-step shfl_xor head-dot reduce,
// coalesced ebias read, online softmax. No atomics, no score buffer.
// ---------------------------------------------------------------------------
__global__ __launch_bounds__(256) void fused_agg(const float* __restrict__ Q,
                                                 const float* __restrict__ K,
                                                 const float* __restrict__ V,
                                                 const float* __restrict__ ebias,
                                                 const int* __restrict__ col_perm,
                                                 const int* __restrict__ offs,
                                                 float* __restrict__ agg) {
    int node = blockIdx.x * 4 + (threadIdx.x >> 6);
    if (node >= NNODES) return;
    int lane = threadIdx.x & 63;
    int h = lane >> 3;
    int start = offs[node];
    int end = offs[node + 1];

    float2 q = *(const float2*)&Q[(size_t)node * 128 + lane * 2];

    float m = -3.0e38f;
    float sum = 0.0f;
    float ax = 0.0f, ay = 0.0f;

    #pragma unroll 4
    for (int i = start; i < end; ++i) {
        int c = col_perm[i];
        float eb = ebias[(size_t)i * 8 + h];
        float2 kv = *(const float2*)&K[(size_t)c * 128 + lane * 2];
        float2 vv = *(const float2*)&V[(size_t)c * 128 + lane * 2];

        float part = q.x * kv.x + q.y * kv.y;
        part += __shfl_xor(part, 1);   // xor 1,2,4 stays within the 8-lane head group
        part += __shfl_xor(part, 2);
        part += __shfl_xor(part, 4);

        float s = part * QK_SCALE + eb;
        float m_new = fmaxf(m, s);
        float corr = __expf(m - m_new);
        float w = __expf(s - m_new);
        sum = sum * corr + w;
        ax = ax * corr + w * vv.x;
        ay = ay * corr + w * vv.y;
        m = m_new;
    }

    float inv = (sum > 0.0f) ? (1.0f / sum) : 0.0f;
    *(float2*)&agg[(size_t)node * 128 + lane * 2] = make_float2(ax * inv, ay * inv);
}

// ---------------------------------------------------------------------------
extern "C" void kernel_launch(void* const* d_in, const int* in_sizes, int n_in,
                              void* d_out, int out_size, void* d_ws, size_t ws_size,
                              hipStream_t stream) {
    const float* node = (const float*)d_in[0];
    const int*   ei   = (const int*)d_in[1];
    const float* ef   = (const float*)d_in[2];
    const float* Wq   = (const float*)d_in[3];
    const float* bq   = (const float*)d_in[4];
    const float* Wk   = (const float*)d_in[5];
    const float* bk   = (const float*)d_in[6];
    const float* Wv   = (const float*)d_in[7];
    const float* bv   = (const float*)d_in[8];
    const float* We   = (const float*)d_in[9];
    const float* be   = (const float*)d_in[10];
    const float* Wo   = (const float*)d_in[11];
    const float* bo   = (const float*)d_in[12];
    float* out = (float*)d_out;

    const int* row = ei;
    const int* col = ei + NEDGES;

    // workspace layout
    float* ws    = (float*)d_ws;
    float* Q     = ws;                                  // NNODES*128
    float* Km    = Q     + (size_t)NNODES * 128;        // NNODES*128
    float* V     = Km    + (size_t)NNODES * 128;        // NNODES*128
    float* ebias = V     + (size_t)NNODES * 128;        // NEDGES*8 (CSR order)
    float* agg   = ebias + (size_t)NEDGES * 8;          // NNODES*128
    int*   cnt      = (int*)(agg + (size_t)NNODES * 128); // NNODES
    int*   offs     = cnt + NNODES;                     // NNODES+1
    int*   cursor   = offs + NNODES + 1;                // NNODES
    int*   rank     = cursor + NNODES;                  // NEDGES
    int*   col_perm = rank + NEDGES;                    // NEDGES

    // CSR build (rebuilt every launch)
    hipMemsetAsync(cnt, 0, (size_t)NNODES * sizeof(int), stream);
    hist_kernel<<<(NEDGES + 255) / 256, 256, 0, stream>>>(row, cnt);
    scan_kernel<<<1, 1024, 0, stream>>>(cnt, offs, cursor);
    scatter_kernel<<<(NEDGES + 255) / 256, 256, 0, stream>>>(row, col, cursor, rank, col_perm);

    dim3 gq((NNODES + TM - 1) / TM, DMODEL / TN);
    gemm128<<<gq, 256, 0, stream>>>(node, Wq, bq, Q,  NNODES, DMODEL);
    gemm128<<<gq, 256, 0, stream>>>(node, Wk, bk, Km, NNODES, DMODEL);
    gemm128<<<gq, 256, 0, stream>>>(node, Wv, bv, V,  NNODES, DMODEL);

    ef_bias_kernel<<<NEDGES * 8 / 256, 256, 0, stream>>>(ef, rank, We, be, ebias);

    fused_agg<<<(NNODES + 3) / 4, 256, 0, stream>>>(Q, Km, V, ebias, col_perm, offs, agg);

    gemm128<<<gq, 256, 0, stream>>>(agg, Wo, bo, out, NNODES, DMODEL);
}

// Round 5
// 562.228 us; speedup vs baseline: 3.0938x; 1.0037x over previous
//
#include <hip/hip_runtime.h>
#include <hip/hip_bf16.h>
#include <math.h>

#define NNODES 50000
#define NEDGES 800000
#define DMODEL 128
#define QK_SCALE 0.25f  // 1/sqrt(16)

typedef float fvec4 __attribute__((ext_vector_type(4)));

// ---------------------------------------------------------------------------
// C[M,N] = A[M,128] @ W[128,N] + bias[N]      (K fixed at 128)
// ---------------------------------------------------------------------------
#define TM 64
#define TN 64
#define TK 32
__global__ __launch_bounds__(256) void gemm128(const float* __restrict__ A,
                                               const float* __restrict__ W,
                                               const float* __restrict__ bias,
                                               float* __restrict__ C,
                                               int M, int N) {
    __shared__ float As[TK][TM + 4];
    __shared__ float Bs[TK][TN + 4];

    int tid = threadIdx.x;
    int bm = blockIdx.x * TM;
    int bn = blockIdx.y * TN;
    int ty = tid >> 4;
    int tx = tid & 15;

    float acc[4][4] = {};

    for (int k0 = 0; k0 < 128; k0 += TK) {
        #pragma unroll
        for (int i = 0; i < 2; ++i) {
            int idx = tid + i * 256;
            int row = idx >> 3;
            int c4  = idx & 7;
            int grow = bm + row;
            if (grow >= M) grow = M - 1;
            float4 v = *(const float4*)&A[(size_t)grow * 128 + k0 + c4 * 4];
            As[c4 * 4 + 0][row] = v.x;
            As[c4 * 4 + 1][row] = v.y;
            As[c4 * 4 + 2][row] = v.z;
            As[c4 * 4 + 3][row] = v.w;
        }
        #pragma unroll
        for (int i = 0; i < 2; ++i) {
            int idx = tid + i * 256;
            int row = idx >> 4;
            int c4  = idx & 15;
            float4 v = *(const float4*)&W[(size_t)(k0 + row) * N + bn + c4 * 4];
            *(float4*)&Bs[row][c4 * 4] = v;
        }
        __syncthreads();

        #pragma unroll
        for (int kk = 0; kk < TK; ++kk) {
            float4 a4 = *(const float4*)&As[kk][ty * 4];
            float4 b4 = *(const float4*)&Bs[kk][tx * 4];
            float av[4] = {a4.x, a4.y, a4.z, a4.w};
            float bv[4] = {b4.x, b4.y, b4.z, b4.w};
            #pragma unroll
            for (int i = 0; i < 4; ++i)
                #pragma unroll
                for (int j = 0; j < 4; ++j)
                    acc[i][j] += av[i] * bv[j];
        }
        __syncthreads();
    }

    float4 bvec = *(const float4*)&bias[bn + tx * 4];
    float bb[4] = {bvec.x, bvec.y, bvec.z, bvec.w};
    #pragma unroll
    for (int i = 0; i < 4; ++i) {
        int gr = bm + ty * 4 + i;
        if (gr < M) {
            float4 o;
            o.x = acc[i][0] + bb[0];
            o.y = acc[i][1] + bb[1];
            o.z = acc[i][2] + bb[2];
            o.w = acc[i][3] + bb[3];
            *(float4*)&C[(size_t)gr * N + bn + tx * 4] = o;
        }
    }
}

// ---------------------------------------------------------------------------
// CSR build: histogram -> scan -> scatter (emits rank & permuted col)
// ---------------------------------------------------------------------------
__global__ __launch_bounds__(256) void hist_kernel(const int* __restrict__ row,
                                                   int* __restrict__ cnt) {
    int e = blockIdx.x * 256 + threadIdx.x;
    if (e < NEDGES) atomicAdd(&cnt[row[e]], 1);
}

__global__ __launch_bounds__(1024) void scan_kernel(const int* __restrict__ cnt,
                                                    int* __restrict__ offs,
                                                    int* __restrict__ cursor) {
    __shared__ int psum[1024];
    int tid = threadIdx.x;
    const int CH = (NNODES + 1023) / 1024;  // 49
    int base = tid * CH;
    int s = 0;
    for (int i = 0; i < CH; ++i) {
        int idx = base + i;
        if (idx < NNODES) s += cnt[idx];
    }
    psum[tid] = s;
    __syncthreads();
    for (int off = 1; off < 1024; off <<= 1) {
        int v = (tid >= off) ? psum[tid - off] : 0;
        __syncthreads();
        psum[tid] += v;
        __syncthreads();
    }
    int running = (tid == 0) ? 0 : psum[tid - 1];
    for (int i = 0; i < CH; ++i) {
        int idx = base + i;
        if (idx < NNODES) {
            offs[idx] = running;
            cursor[idx] = running;
            running += cnt[idx];
        }
    }
    if (tid == 0) offs[NNODES] = NEDGES;
}

__global__ __launch_bounds__(256) void scatter_kernel(const int* __restrict__ row,
                                                      const int* __restrict__ col,
                                                      int* __restrict__ cursor,
                                                      int* __restrict__ rank,
                                                      int* __restrict__ col_perm) {
    int e = blockIdx.x * 256 + threadIdx.x;
    if (e < NEDGES) {
        int pos = atomicAdd(&cursor[row[e]], 1);
        rank[e] = pos;
        col_perm[pos] = col[e];
    }
}

// ---------------------------------------------------------------------------
// ebias[pos,h] = ef[e,:] . We[:,h] + be[h]   written in CSR order (pos=rank[e])
// ---------------------------------------------------------------------------
__global__ __launch_bounds__(256) void ef_bias_kernel(const float* __restrict__ EF,
                                                      const int* __restrict__ rank,
                                                      const float* __restrict__ We,
                                                      const float* __restrict__ be,
                                                      float* __restrict__ ebias) {
    __shared__ float sWe[8][128];   // [h][d]
    __shared__ float sbe[8];
    for (int i = threadIdx.x; i < 1024; i += 256) {
        int d = i >> 3, h = i & 7;
        sWe[h][d] = We[i];          // We is [d][h] row-major: We[d*8+h]
    }
    if (threadIdx.x < 8) sbe[threadIdx.x] = be[threadIdx.x];
    __syncthreads();

    int g = blockIdx.x * 256 + threadIdx.x;   // NEDGES*8 threads
    int e = g >> 3;
    int s = g & 7;
    if (e >= NEDGES) return;

    const fvec4* efv = (const fvec4*)(EF + (size_t)e * 128);
    float acc[8] = {0.f, 0.f, 0.f, 0.f, 0.f, 0.f, 0.f, 0.f};
    #pragma unroll
    for (int i = 0; i < 4; ++i) {
        int d4 = s + 8 * i;
        fvec4 v = __builtin_nontemporal_load(&efv[d4]);
        #pragma unroll
        for (int h = 0; h < 8; ++h) {
            fvec4 w = *(const fvec4*)&sWe[h][d4 * 4];
            acc[h] += v.x * w.x + v.y * w.y + v.z * w.z + v.w * w.w;
        }
    }

    #pragma unroll
    for (int off = 1; off < 8; off <<= 1)
        #pragma unroll
        for (int h = 0; h < 8; ++h)
            acc[h] += __shfl_xor(acc[h], off);

    int pos = rank[e];
    ebias[(size_t)pos * 8 + s] = acc[s] + sbe[s];
}

// ---------------------------------------------------------------------------
// fused QK^T + online segment softmax + PV, lane-local heads.
// wave = 1 node. lane = slot*8 + h (slot=lane>>3, head h=lane&7).
// Lane owns ALL 16 dims of head h for edge-slot s: K/V rows gathered as
// 4xfloat4, dot is lane-local (NO per-edge shfl). 8 edges in flight per wave.
// Per-slot online-softmax states merged once per node via 3-step shfl_xor
// tree (online softmax is associative). Slot-0 lanes write the output row.
// ---------------------------------------------------------------------------
__global__ __launch_bounds__(256) void fused_agg(const float* __restrict__ Q,
                                                 const float* __restrict__ K,
                                                 const float* __restrict__ V,
                                                 const float* __restrict__ ebias,
                                                 const int* __restrict__ col_perm,
                                                 const int* __restrict__ offs,
                                                 float* __restrict__ agg) {
    int node = blockIdx.x * 4 + (threadIdx.x >> 6);
    if (node >= NNODES) return;
    int lane = threadIdx.x & 63;
    int slot = lane >> 3;
    int h    = lane & 7;
    int start = offs[node];
    int end   = offs[node + 1];

    // Q fragment: 16 floats of head h (same for all 8 slots -> broadcast reads)
    const fvec4* qp = (const fvec4*)(Q + (size_t)node * 128 + h * 16);
    fvec4 q0 = qp[0], q1 = qp[1], q2 = qp[2], q3 = qp[3];

    float m = -3.0e38f;
    float sum = 0.0f;
    fvec4 a0 = {0.f,0.f,0.f,0.f}, a1 = {0.f,0.f,0.f,0.f};
    fvec4 a2 = {0.f,0.f,0.f,0.f}, a3 = {0.f,0.f,0.f,0.f};

    for (int i = start + slot; i < end; i += 8) {
        int c = col_perm[i];
        float eb = ebias[(size_t)i * 8 + h];   // wave-contiguous
        const fvec4* kp = (const fvec4*)(K + (size_t)c * 128 + h * 16);
        const fvec4* vp = (const fvec4*)(V + (size_t)c * 128 + h * 16);
        fvec4 k0 = kp[0], k1 = kp[1], k2 = kp[2], k3 = kp[3];
        fvec4 v0 = vp[0], v1 = vp[1], v2 = vp[2], v3 = vp[3];

        fvec4 d4 = q0 * k0 + q1 * k1 + q2 * k2 + q3 * k3;
        float dot = d4.x + d4.y + d4.z + d4.w;

        float s = dot * QK_SCALE + eb;
        float mn = fmaxf(m, s);
        float corr = __expf(m - mn);
        float w = __expf(s - mn);
        sum = sum * corr + w;
        a0 = a0 * corr + w * v0;
        a1 = a1 * corr + w * v1;
        a2 = a2 * corr + w * v2;
        a3 = a3 * corr + w * v3;
        m = mn;
    }

    // merge the 8 slot-states (same h) across lane bits 3..5
    #pragma unroll
    for (int off = 8; off < 64; off <<= 1) {
        float mo = __shfl_xor(m, off);
        float so = __shfl_xor(sum, off);
        fvec4 b0, b1, b2, b3;
        b0.x = __shfl_xor(a0.x, off); b0.y = __shfl_xor(a0.y, off);
        b0.z = __shfl_xor(a0.z, off); b0.w = __shfl_xor(a0.w, off);
        b1.x = __shfl_xor(a1.x, off); b1.y = __shfl_xor(a1.y, off);
        b1.z = __shfl_xor(a1.z, off); b1.w = __shfl_xor(a1.w, off);
        b2.x = __shfl_xor(a2.x, off); b2.y = __shfl_xor(a2.y, off);
        b2.z = __shfl_xor(a2.z, off); b2.w = __shfl_xor(a2.w, off);
        b3.x = __shfl_xor(a3.x, off); b3.y = __shfl_xor(a3.y, off);
        b3.z = __shfl_xor(a3.z, off); b3.w = __shfl_xor(a3.w, off);
        float M = fmaxf(m, mo);
        float c1 = __expf(m - M);
        float c2 = __expf(mo - M);
        sum = sum * c1 + so * c2;
        a0 = a0 * c1 + b0 * c2;
        a1 = a1 * c1 + b1 * c2;
        a2 = a2 * c1 + b2 * c2;
        a3 = a3 * c1 + b3 * c2;
        m = M;
    }

    if (slot == 0) {
        float inv = (sum > 0.0f) ? (1.0f / sum) : 0.0f;
        fvec4* op = (fvec4*)(agg + (size_t)node * 128 + h * 16);
        op[0] = a0 * inv;
        op[1] = a1 * inv;
        op[2] = a2 * inv;
        op[3] = a3 * inv;
    }
}

// ---------------------------------------------------------------------------
extern "C" void kernel_launch(void* const* d_in, const int* in_sizes, int n_in,
                              void* d_out, int out_size, void* d_ws, size_t ws_size,
                              hipStream_t stream) {
    const float* node = (const float*)d_in[0];
    const int*   ei   = (const int*)d_in[1];
    const float* ef   = (const float*)d_in[2];
    const float* Wq   = (const float*)d_in[3];
    const float* bq   = (const float*)d_in[4];
    const float* Wk   = (const float*)d_in[5];
    const float* bk   = (const float*)d_in[6];
    const float* Wv   = (const float*)d_in[7];
    const float* bv   = (const float*)d_in[8];
    const float* We   = (const float*)d_in[9];
    const float* be   = (const float*)d_in[10];
    const float* Wo   = (const float*)d_in[11];
    const float* bo   = (const float*)d_in[12];
    float* out = (float*)d_out;

    const int* row = ei;
    const int* col = ei + NEDGES;

    // workspace layout
    float* ws    = (float*)d_ws;
    float* Q     = ws;                                  // NNODES*128
    float* Km    = Q     + (size_t)NNODES * 128;        // NNODES*128
    float* V     = Km    + (size_t)NNODES * 128;        // NNODES*128
    float* ebias = V     + (size_t)NNODES * 128;        // NEDGES*8 (CSR order)
    float* agg   = ebias + (size_t)NEDGES * 8;          // NNODES*128
    int*   cnt      = (int*)(agg + (size_t)NNODES * 128); // NNODES
    int*   offs     = cnt + NNODES;                     // NNODES+1
    int*   cursor   = offs + NNODES + 1;                // NNODES
    int*   rank     = cursor + NNODES;                  // NEDGES
    int*   col_perm = rank + NEDGES;                    // NEDGES

    // CSR build (rebuilt every launch)
    hipMemsetAsync(cnt, 0, (size_t)NNODES * sizeof(int), stream);
    hist_kernel<<<(NEDGES + 255) / 256, 256, 0, stream>>>(row, cnt);
    scan_kernel<<<1, 1024, 0, stream>>>(cnt, offs, cursor);
    scatter_kernel<<<(NEDGES + 255) / 256, 256, 0, stream>>>(row, col, cursor, rank, col_perm);

    dim3 gq((NNODES + TM - 1) / TM, DMODEL / TN);
    gemm128<<<gq, 256, 0, stream>>>(node, Wq, bq, Q,  NNODES, DMODEL);
    gemm128<<<gq, 256, 0, stream>>>(node, Wk, bk, Km, NNODES, DMODEL);
    gemm128<<<gq, 256, 0, stream>>>(node, Wv, bv, V,  NNODES, DMODEL);

    ef_bias_kernel<<<NEDGES * 8 / 256, 256, 0, stream>>>(ef, rank, We, be, ebias);

    fused_agg<<<(NNODES + 3) / 4, 256, 0, stream>>>(Q, Km, V, ebias, col_perm, offs, agg);

    gemm128<<<gq, 256, 0, stream>>>(agg, Wo, bo, out, NNODES, DMODEL);
}

// Round 7
// 549.295 us; speedup vs baseline: 3.1667x; 1.0235x over previous
//
#include <hip/hip_runtime.h>
#include <hip/hip_bf16.h>
#include <math.h>

#define NNODES 50000
#define NEDGES 800000
#define DMODEL 128
#define QK_SCALE 0.25f  // 1/sqrt(16)

typedef float fvec4 __attribute__((ext_vector_type(4)));

// ---------------------------------------------------------------------------
// C[gr*ldc + coff + n] = A[M,128] @ W[128,N] + bias[N]      (K fixed at 128)
// ldc/coff let K and V write into an interleaved KV[node][256] layout.
// ---------------------------------------------------------------------------
#define TM 64
#define TN 64
#define TK 32
__global__ __launch_bounds__(256) void gemm128(const float* __restrict__ A,
                                               const float* __restrict__ W,
                                               const float* __restrict__ bias,
                                               float* __restrict__ C,
                                               int M, int N, int ldc, int coff) {
    __shared__ float As[TK][TM + 4];
    __shared__ float Bs[TK][TN + 4];

    int tid = threadIdx.x;
    int bm = blockIdx.x * TM;
    int bn = blockIdx.y * TN;
    int ty = tid >> 4;
    int tx = tid & 15;

    float acc[4][4] = {};

    for (int k0 = 0; k0 < 128; k0 += TK) {
        #pragma unroll
        for (int i = 0; i < 2; ++i) {
            int idx = tid + i * 256;
            int row = idx >> 3;
            int c4  = idx & 7;
            int grow = bm + row;
            if (grow >= M) grow = M - 1;
            float4 v = *(const float4*)&A[(size_t)grow * 128 + k0 + c4 * 4];
            As[c4 * 4 + 0][row] = v.x;
            As[c4 * 4 + 1][row] = v.y;
            As[c4 * 4 + 2][row] = v.z;
            As[c4 * 4 + 3][row] = v.w;
        }
        #pragma unroll
        for (int i = 0; i < 2; ++i) {
            int idx = tid + i * 256;
            int row = idx >> 4;
            int c4  = idx & 15;
            float4 v = *(const float4*)&W[(size_t)(k0 + row) * N + bn + c4 * 4];
            *(float4*)&Bs[row][c4 * 4] = v;
        }
        __syncthreads();

        #pragma unroll
        for (int kk = 0; kk < TK; ++kk) {
            float4 a4 = *(const float4*)&As[kk][ty * 4];
            float4 b4 = *(const float4*)&Bs[kk][tx * 4];
            float av[4] = {a4.x, a4.y, a4.z, a4.w};
            float bv[4] = {b4.x, b4.y, b4.z, b4.w};
            #pragma unroll
            for (int i = 0; i < 4; ++i)
                #pragma unroll
                for (int j = 0; j < 4; ++j)
                    acc[i][j] += av[i] * bv[j];
        }
        __syncthreads();
    }

    float4 bvec = *(const float4*)&bias[bn + tx * 4];
    float bb[4] = {bvec.x, bvec.y, bvec.z, bvec.w};
    #pragma unroll
    for (int i = 0; i < 4; ++i) {
        int gr = bm + ty * 4 + i;
        if (gr < M) {
            float4 o;
            o.x = acc[i][0] + bb[0];
            o.y = acc[i][1] + bb[1];
            o.z = acc[i][2] + bb[2];
            o.w = acc[i][3] + bb[3];
            *(float4*)&C[(size_t)gr * ldc + coff + bn + tx * 4] = o;
        }
    }
}

// ---------------------------------------------------------------------------
// CSR build: zero -> histogram -> scan -> scatter (emits rank & permuted col)
// ---------------------------------------------------------------------------
__global__ __launch_bounds__(256) void zero_cnt(int* __restrict__ cnt) {
    int i = blockIdx.x * 256 + threadIdx.x;
    if (i < NNODES) cnt[i] = 0;
}

__global__ __launch_bounds__(256) void hist_kernel(const int* __restrict__ row,
                                                   int* __restrict__ cnt) {
    int e = blockIdx.x * 256 + threadIdx.x;
    if (e < NEDGES) atomicAdd(&cnt[row[e]], 1);
}

__global__ __launch_bounds__(1024) void scan_kernel(const int* __restrict__ cnt,
                                                    int* __restrict__ offs,
                                                    int* __restrict__ cursor) {
    __shared__ int psum[1024];
    int tid = threadIdx.x;
    const int CH = (NNODES + 1023) / 1024;  // 49
    int base = tid * CH;
    int s = 0;
    for (int i = 0; i < CH; ++i) {
        int idx = base + i;
        if (idx < NNODES) s += cnt[idx];
    }
    psum[tid] = s;
    __syncthreads();
    for (int off = 1; off < 1024; off <<= 1) {
        int v = (tid >= off) ? psum[tid - off] : 0;
        __syncthreads();
        psum[tid] += v;
        __syncthreads();
    }
    int running = (tid == 0) ? 0 : psum[tid - 1];
    for (int i = 0; i < CH; ++i) {
        int idx = base + i;
        if (idx < NNODES) {
            offs[idx] = running;
            cursor[idx] = running;
            running += cnt[idx];
        }
    }
    if (tid == 0) offs[NNODES] = NEDGES;
}

__global__ __launch_bounds__(256) void scatter_kernel(const int* __restrict__ row,
                                                      const int* __restrict__ col,
                                                      int* __restrict__ cursor,
                                                      int* __restrict__ rank,
                                                      int* __restrict__ col_perm) {
    int e = blockIdx.x * 256 + threadIdx.x;
    if (e < NEDGES) {
        int pos = atomicAdd(&cursor[row[e]], 1);
        rank[e] = pos;
        col_perm[pos] = col[e];
    }
}

// ---------------------------------------------------------------------------
// ebias[pos,h] = ef[e,:] . We[:,h] + be[h]   written in CSR order (pos=rank[e])
// ---------------------------------------------------------------------------
__global__ __launch_bounds__(256) void ef_bias_kernel(const float* __restrict__ EF,
                                                      const int* __restrict__ rank,
                                                      const float* __restrict__ We,
                                                      const float* __restrict__ be,
                                                      float* __restrict__ ebias) {
    __shared__ float sWe[8][128];   // [h][d]
    __shared__ float sbe[8];
    for (int i = threadIdx.x; i < 1024; i += 256) {
        int d = i >> 3, h = i & 7;
        sWe[h][d] = We[i];          // We is [d][h] row-major: We[d*8+h]
    }
    if (threadIdx.x < 8) sbe[threadIdx.x] = be[threadIdx.x];
    __syncthreads();

    int g = blockIdx.x * 256 + threadIdx.x;   // NEDGES*8 threads
    int e = g >> 3;
    int s = g & 7;
    if (e >= NEDGES) return;

    const fvec4* efv = (const fvec4*)(EF + (size_t)e * 128);
    float acc[8] = {0.f, 0.f, 0.f, 0.f, 0.f, 0.f, 0.f, 0.f};
    #pragma unroll
    for (int i = 0; i < 4; ++i) {
        int d4 = s + 8 * i;
        fvec4 v = __builtin_nontemporal_load(&efv[d4]);
        #pragma unroll
        for (int h = 0; h < 8; ++h) {
            fvec4 w = *(const fvec4*)&sWe[h][d4 * 4];
            acc[h] += v.x * w.x + v.y * w.y + v.z * w.z + v.w * w.w;
        }
    }

    #pragma unroll
    for (int off = 1; off < 8; off <<= 1)
        #pragma unroll
        for (int h = 0; h < 8; ++h)
            acc[h] += __shfl_xor(acc[h], off);

    int pos = rank[e];
    ebias[(size_t)pos * 8 + s] = acc[s] + sbe[s];
}

// ---------------------------------------------------------------------------
// fused QK^T + online segment softmax + PV, lane-local heads.
// wave = 1 node; lane = slot*8 + h. Lane owns all 16 dims of head h for
// edge-slot s. KV interleaved: one contiguous 1KB block per edge gather.
// V half lives at float offset 128 = fvec4 offset 32 (NOT +8 — r6 bug).
// ---------------------------------------------------------------------------
__global__ __launch_bounds__(256) void fused_agg(const float* __restrict__ Q,
                                                 const float* __restrict__ KV,
                                                 const float* __restrict__ ebias,
                                                 const int* __restrict__ col_perm,
                                                 const int* __restrict__ offs,
                                                 float* __restrict__ agg) {
    int node = blockIdx.x * 4 + (threadIdx.x >> 6);
    if (node >= NNODES) return;
    int lane = threadIdx.x & 63;
    int slot = lane >> 3;
    int h    = lane & 7;
    int start = offs[node];
    int end   = offs[node + 1];

    const fvec4* qp = (const fvec4*)(Q + (size_t)node * 128 + h * 16);
    fvec4 q0 = qp[0], q1 = qp[1], q2 = qp[2], q3 = qp[3];

    float m = -3.0e38f;
    float sum = 0.0f;
    fvec4 a0 = {0.f,0.f,0.f,0.f}, a1 = {0.f,0.f,0.f,0.f};
    fvec4 a2 = {0.f,0.f,0.f,0.f}, a3 = {0.f,0.f,0.f,0.f};

    for (int i = start + slot; i < end; i += 8) {
        int c = col_perm[i];
        float eb = ebias[(size_t)i * 8 + h];   // wave-contiguous
        const fvec4* kp = (const fvec4*)(KV + (size_t)c * 256 + h * 16);
        const fvec4* vp = kp + 32;             // V half: +128 floats = +32 fvec4
        fvec4 k0 = kp[0], k1 = kp[1], k2 = kp[2], k3 = kp[3];
        fvec4 v0 = vp[0], v1 = vp[1], v2 = vp[2], v3 = vp[3];

        fvec4 d4 = q0 * k0 + q1 * k1 + q2 * k2 + q3 * k3;
        float dot = d4.x + d4.y + d4.z + d4.w;

        float s = dot * QK_SCALE + eb;
        float mn = fmaxf(m, s);
        float corr = __expf(m - mn);
        float w = __expf(s - mn);
        sum = sum * corr + w;
        a0 = a0 * corr + w * v0;
        a1 = a1 * corr + w * v1;
        a2 = a2 * corr + w * v2;
        a3 = a3 * corr + w * v3;
        m = mn;
    }

    // merge the 8 slot-states (same h) across lane bits 3..5
    #pragma unroll
    for (int off = 8; off < 64; off <<= 1) {
        float mo = __shfl_xor(m, off);
        float so = __shfl_xor(sum, off);
        fvec4 b0, b1, b2, b3;
        b0.x = __shfl_xor(a0.x, off); b0.y = __shfl_xor(a0.y, off);
        b0.z = __shfl_xor(a0.z, off); b0.w = __shfl_xor(a0.w, off);
        b1.x = __shfl_xor(a1.x, off); b1.y = __shfl_xor(a1.y, off);
        b1.z = __shfl_xor(a1.z, off); b1.w = __shfl_xor(a1.w, off);
        b2.x = __shfl_xor(a2.x, off); b2.y = __shfl_xor(a2.y, off);
        b2.z = __shfl_xor(a2.z, off); b2.w = __shfl_xor(a2.w, off);
        b3.x = __shfl_xor(a3.x, off); b3.y = __shfl_xor(a3.y, off);
        b3.z = __shfl_xor(a3.z, off); b3.w = __shfl_xor(a3.w, off);
        float M = fmaxf(m, mo);
        float c1 = __expf(m - M);
        float c2 = __expf(mo - M);
        sum = sum * c1 + so * c2;
        a0 = a0 * c1 + b0 * c2;
        a1 = a1 * c1 + b1 * c2;
        a2 = a2 * c1 + b2 * c2;
        a3 = a3 * c1 + b3 * c2;
        m = M;
    }

    if (slot == 0) {
        float inv = (sum > 0.0f) ? (1.0f / sum) : 0.0f;
        fvec4* op = (fvec4*)(agg + (size_t)node * 128 + h * 16);
        op[0] = a0 * inv;
        op[1] = a1 * inv;
        op[2] = a2 * inv;
        op[3] = a3 * inv;
    }
}

// ---------------------------------------------------------------------------
extern "C" void kernel_launch(void* const* d_in, const int* in_sizes, int n_in,
                              void* d_out, int out_size, void* d_ws, size_t ws_size,
                              hipStream_t stream) {
    const float* node = (const float*)d_in[0];
    const int*   ei   = (const int*)d_in[1];
    const float* ef   = (const float*)d_in[2];
    const float* Wq   = (const float*)d_in[3];
    const float* bq   = (const float*)d_in[4];
    const float* Wk   = (const float*)d_in[5];
    const float* bk   = (const float*)d_in[6];
    const float* Wv   = (const float*)d_in[7];
    const float* bv   = (const float*)d_in[8];
    const float* We   = (const float*)d_in[9];
    const float* be   = (const float*)d_in[10];
    const float* Wo   = (const float*)d_in[11];
    const float* bo   = (const float*)d_in[12];
    float* out = (float*)d_out;

    const int* row = ei;
    const int* col = ei + NEDGES;

    // workspace layout
    float* ws    = (float*)d_ws;
    float* Q     = ws;                                  // NNODES*128
    float* KV    = Q     + (size_t)NNODES * 128;        // NNODES*256 (K|V interleaved)
    float* ebias = KV    + (size_t)NNODES * 256;        // NEDGES*8 (CSR order)
    float* agg   = ebias + (size_t)NEDGES * 8;          // NNODES*128
    int*   cnt      = (int*)(agg + (size_t)NNODES * 128); // NNODES
    int*   offs     = cnt + NNODES;                     // NNODES+1
    int*   cursor   = offs + NNODES + 1;                // NNODES
    int*   rank     = cursor + NNODES;                  // NEDGES
    int*   col_perm = rank + NEDGES;                    // NEDGES

    // CSR build (rebuilt every launch; no runtime fill nodes)
    zero_cnt<<<(NNODES + 255) / 256, 256, 0, stream>>>(cnt);
    hist_kernel<<<(NEDGES + 255) / 256, 256, 0, stream>>>(row, cnt);
    scan_kernel<<<1, 1024, 0, stream>>>(cnt, offs, cursor);
    scatter_kernel<<<(NEDGES + 255) / 256, 256, 0, stream>>>(row, col, cursor, rank, col_perm);

    dim3 gq((NNODES + TM - 1) / TM, DMODEL / TN);
    gemm128<<<gq, 256, 0, stream>>>(node, Wq, bq, Q,  NNODES, DMODEL, 128, 0);
    gemm128<<<gq, 256, 0, stream>>>(node, Wk, bk, KV, NNODES, DMODEL, 256, 0);
    gemm128<<<gq, 256, 0, stream>>>(node, Wv, bv, KV, NNODES, DMODEL, 256, 128);

    ef_bias_kernel<<<NEDGES * 8 / 256, 256, 0, stream>>>(ef, rank, We, be, ebias);

    fused_agg<<<(NNODES + 3) / 4, 256, 0, stream>>>(Q, KV, ebias, col_perm, offs, agg);

    gemm128<<<gq, 256, 0, stream>>>(agg, Wo, bo, out, NNODES, DMODEL, 128, 0);
}

// Round 8
// 505.059 us; speedup vs baseline: 3.4440x; 1.0876x over previous
//
#include <hip/hip_runtime.h>
#include <hip/hip_bf16.h>
#include <math.h>

#define NNODES 50000
#define NEDGES 800000
#define DMODEL 128
#define QK_SCALE 0.25f  // 1/sqrt(16)

typedef float fvec4 __attribute__((ext_vector_type(4)));

__device__ __forceinline__ unsigned short f2bf(float f) {
    unsigned int u = __float_as_uint(f);
    unsigned int r = (u + 0x7FFFu + ((u >> 16) & 1u)) >> 16;   // round-to-nearest-even
    return (unsigned short)r;
}

// convert 8 packed bf16 (one uint4) -> two fvec4 (elements in memory order)
__device__ __forceinline__ void bf8_to_f32(uint4 u, fvec4& lo, fvec4& hi) {
    lo.x = __uint_as_float(u.x << 16); lo.y = __uint_as_float(u.x & 0xFFFF0000u);
    lo.z = __uint_as_float(u.y << 16); lo.w = __uint_as_float(u.y & 0xFFFF0000u);
    hi.x = __uint_as_float(u.z << 16); hi.y = __uint_as_float(u.z & 0xFFFF0000u);
    hi.z = __uint_as_float(u.w << 16); hi.w = __uint_as_float(u.w & 0xFFFF0000u);
}

// ---------------------------------------------------------------------------
// C[gr*ldc + coff + n] = A[M,128] @ W[128,N] + bias[N]      (K fixed at 128)
// BF16OUT=false: C is float*. BF16OUT=true: C is ushort* (bf16, RNE).
// ---------------------------------------------------------------------------
#define TM 64
#define TN 64
#define TK 32
template<bool BF16OUT>
__global__ __launch_bounds__(256) void gemm128(const float* __restrict__ A,
                                               const float* __restrict__ W,
                                               const float* __restrict__ bias,
                                               void* __restrict__ C,
                                               int M, int N, int ldc, int coff) {
    __shared__ float As[TK][TM + 4];
    __shared__ float Bs[TK][TN + 4];

    int tid = threadIdx.x;
    int bm = blockIdx.x * TM;
    int bn = blockIdx.y * TN;
    int ty = tid >> 4;
    int tx = tid & 15;

    float acc[4][4] = {};

    for (int k0 = 0; k0 < 128; k0 += TK) {
        #pragma unroll
        for (int i = 0; i < 2; ++i) {
            int idx = tid + i * 256;
            int row = idx >> 3;
            int c4  = idx & 7;
            int grow = bm + row;
            if (grow >= M) grow = M - 1;
            float4 v = *(const float4*)&A[(size_t)grow * 128 + k0 + c4 * 4];
            As[c4 * 4 + 0][row] = v.x;
            As[c4 * 4 + 1][row] = v.y;
            As[c4 * 4 + 2][row] = v.z;
            As[c4 * 4 + 3][row] = v.w;
        }
        #pragma unroll
        for (int i = 0; i < 2; ++i) {
            int idx = tid + i * 256;
            int row = idx >> 4;
            int c4  = idx & 15;
            float4 v = *(const float4*)&W[(size_t)(k0 + row) * N + bn + c4 * 4];
            *(float4*)&Bs[row][c4 * 4] = v;
        }
        __syncthreads();

        #pragma unroll
        for (int kk = 0; kk < TK; ++kk) {
            float4 a4 = *(const float4*)&As[kk][ty * 4];
            float4 b4 = *(const float4*)&Bs[kk][tx * 4];
            float av[4] = {a4.x, a4.y, a4.z, a4.w};
            float bv[4] = {b4.x, b4.y, b4.z, b4.w};
            #pragma unroll
            for (int i = 0; i < 4; ++i)
                #pragma unroll
                for (int j = 0; j < 4; ++j)
                    acc[i][j] += av[i] * bv[j];
        }
        __syncthreads();
    }

    float4 bvec = *(const float4*)&bias[bn + tx * 4];
    float bb[4] = {bvec.x, bvec.y, bvec.z, bvec.w};
    #pragma unroll
    for (int i = 0; i < 4; ++i) {
        int gr = bm + ty * 4 + i;
        if (gr < M) {
            float o0 = acc[i][0] + bb[0];
            float o1 = acc[i][1] + bb[1];
            float o2 = acc[i][2] + bb[2];
            float o3 = acc[i][3] + bb[3];
            if (BF16OUT) {
                ushort4 s;
                s.x = f2bf(o0); s.y = f2bf(o1); s.z = f2bf(o2); s.w = f2bf(o3);
                *(ushort4*)((unsigned short*)C + (size_t)gr * ldc + coff + bn + tx * 4) = s;
            } else {
                float4 o = {o0, o1, o2, o3};
                *(float4*)((float*)C + (size_t)gr * ldc + coff + bn + tx * 4) = o;
            }
        }
    }
}

// ---------------------------------------------------------------------------
// CSR build: zero -> histogram -> scan -> scatter (emits rank & permuted col)
// ---------------------------------------------------------------------------
__global__ __launch_bounds__(256) void zero_cnt(int* __restrict__ cnt) {
    int i = blockIdx.x * 256 + threadIdx.x;
    if (i < NNODES) cnt[i] = 0;
}

__global__ __launch_bounds__(256) void hist_kernel(const int* __restrict__ row,
                                                   int* __restrict__ cnt) {
    int e = blockIdx.x * 256 + threadIdx.x;
    if (e < NEDGES) atomicAdd(&cnt[row[e]], 1);
}

__global__ __launch_bounds__(1024) void scan_kernel(const int* __restrict__ cnt,
                                                    int* __restrict__ offs,
                                                    int* __restrict__ cursor) {
    __shared__ int psum[1024];
    int tid = threadIdx.x;
    const int CH = (NNODES + 1023) / 1024;  // 49
    int base = tid * CH;
    int s = 0;
    for (int i = 0; i < CH; ++i) {
        int idx = base + i;
        if (idx < NNODES) s += cnt[idx];
    }
    psum[tid] = s;
    __syncthreads();
    for (int off = 1; off < 1024; off <<= 1) {
        int v = (tid >= off) ? psum[tid - off] : 0;
        __syncthreads();
        psum[tid] += v;
        __syncthreads();
    }
    int running = (tid == 0) ? 0 : psum[tid - 1];
    for (int i = 0; i < CH; ++i) {
        int idx = base + i;
        if (idx < NNODES) {
            offs[idx] = running;
            cursor[idx] = running;
            running += cnt[idx];
        }
    }
    if (tid == 0) offs[NNODES] = NEDGES;
}

__global__ __launch_bounds__(256) void scatter_kernel(const int* __restrict__ row,
                                                      const int* __restrict__ col,
                                                      int* __restrict__ cursor,
                                                      int* __restrict__ rank,
                                                      int* __restrict__ col_perm) {
    int e = blockIdx.x * 256 + threadIdx.x;
    if (e < NEDGES) {
        int pos = atomicAdd(&cursor[row[e]], 1);
        rank[e] = pos;
        col_perm[pos] = col[e];
    }
}

// ---------------------------------------------------------------------------
// ebias[pos,h] = ef[e,:] . We[:,h] + be[h]   written in CSR order (pos=rank[e])
// ---------------------------------------------------------------------------
__global__ __launch_bounds__(256) void ef_bias_kernel(const float* __restrict__ EF,
                                                      const int* __restrict__ rank,
                                                      const float* __restrict__ We,
                                                      const float* __restrict__ be,
                                                      float* __restrict__ ebias) {
    __shared__ float sWe[8][128];   // [h][d]
    __shared__ float sbe[8];
    for (int i = threadIdx.x; i < 1024; i += 256) {
        int d = i >> 3, h = i & 7;
        sWe[h][d] = We[i];          // We is [d][h] row-major: We[d*8+h]
    }
    if (threadIdx.x < 8) sbe[threadIdx.x] = be[threadIdx.x];
    __syncthreads();

    int g = blockIdx.x * 256 + threadIdx.x;   // NEDGES*8 threads
    int e = g >> 3;
    int s = g & 7;
    if (e >= NEDGES) return;

    const fvec4* efv = (const fvec4*)(EF + (size_t)e * 128);
    float acc[8] = {0.f, 0.f, 0.f, 0.f, 0.f, 0.f, 0.f, 0.f};
    #pragma unroll
    for (int i = 0; i < 4; ++i) {
        int d4 = s + 8 * i;
        fvec4 v = __builtin_nontemporal_load(&efv[d4]);
        #pragma unroll
        for (int h = 0; h < 8; ++h) {
            fvec4 w = *(const fvec4*)&sWe[h][d4 * 4];
            acc[h] += v.x * w.x + v.y * w.y + v.z * w.z + v.w * w.w;
        }
    }

    #pragma unroll
    for (int off = 1; off < 8; off <<= 1)
        #pragma unroll
        for (int h = 0; h < 8; ++h)
            acc[h] += __shfl_xor(acc[h], off);

    int pos = rank[e];
    ebias[(size_t)pos * 8 + s] = acc[s] + sbe[s];
}

// ---------------------------------------------------------------------------
// fused QK^T + online segment softmax + PV, lane-local heads, bf16 KV.
// wave = 1 node; lane = slot*8 + h. Lane owns all 16 dims of head h for
// edge-slot s. KV row = 256 bf16 (K:0-127, V:128-255) = 512B per node.
// ---------------------------------------------------------------------------
__global__ __launch_bounds__(256) void fused_agg(const float* __restrict__ Q,
                                                 const unsigned short* __restrict__ KV,
                                                 const float* __restrict__ ebias,
                                                 const int* __restrict__ col_perm,
                                                 const int* __restrict__ offs,
                                                 float* __restrict__ agg) {
    int node = blockIdx.x * 4 + (threadIdx.x >> 6);
    if (node >= NNODES) return;
    int lane = threadIdx.x & 63;
    int slot = lane >> 3;
    int h    = lane & 7;
    int start = offs[node];
    int end   = offs[node + 1];

    const fvec4* qp = (const fvec4*)(Q + (size_t)node * 128 + h * 16);
    fvec4 q0 = qp[0], q1 = qp[1], q2 = qp[2], q3 = qp[3];

    float m = -3.0e38f;
    float sum = 0.0f;
    fvec4 a0 = {0.f,0.f,0.f,0.f}, a1 = {0.f,0.f,0.f,0.f};
    fvec4 a2 = {0.f,0.f,0.f,0.f}, a3 = {0.f,0.f,0.f,0.f};

    for (int i = start + slot; i < end; i += 8) {
        int c = col_perm[i];
        float eb = ebias[(size_t)i * 8 + h];   // wave-contiguous
        // element offset h*16 in a 256-elem row; uint4 = 8 bf16
        const uint4* kp = (const uint4*)(KV + (size_t)c * 256 + h * 16);
        uint4 ku0 = kp[0],  ku1 = kp[1];       // K[h*16 .. h*16+15]
        uint4 vu0 = kp[16], vu1 = kp[17];      // V half: +128 elems = +16 uint4
        fvec4 k0, k1, k2, k3, v0, v1, v2, v3;
        bf8_to_f32(ku0, k0, k1);
        bf8_to_f32(ku1, k2, k3);
        bf8_to_f32(vu0, v0, v1);
        bf8_to_f32(vu1, v2, v3);

        fvec4 d4 = q0 * k0 + q1 * k1 + q2 * k2 + q3 * k3;
        float dot = d4.x + d4.y + d4.z + d4.w;

        float s = dot * QK_SCALE + eb;
        float mn = fmaxf(m, s);
        float corr = __expf(m - mn);
        float w = __expf(s - mn);
        sum = sum * corr + w;
        a0 = a0 * corr + w * v0;
        a1 = a1 * corr + w * v1;
        a2 = a2 * corr + w * v2;
        a3 = a3 * corr + w * v3;
        m = mn;
    }

    // merge the 8 slot-states (same h) across lane bits 3..5
    #pragma unroll
    for (int off = 8; off < 64; off <<= 1) {
        float mo = __shfl_xor(m, off);
        float so = __shfl_xor(sum, off);
        fvec4 b0, b1, b2, b3;
        b0.x = __shfl_xor(a0.x, off); b0.y = __shfl_xor(a0.y, off);
        b0.z = __shfl_xor(a0.z, off); b0.w = __shfl_xor(a0.w, off);
        b1.x = __shfl_xor(a1.x, off); b1.y = __shfl_xor(a1.y, off);
        b1.z = __shfl_xor(a1.z, off); b1.w = __shfl_xor(a1.w, off);
        b2.x = __shfl_xor(a2.x, off); b2.y = __shfl_xor(a2.y, off);
        b2.z = __shfl_xor(a2.z, off); b2.w = __shfl_xor(a2.w, off);
        b3.x = __shfl_xor(a3.x, off); b3.y = __shfl_xor(a3.y, off);
        b3.z = __shfl_xor(a3.z, off); b3.w = __shfl_xor(a3.w, off);
        float M = fmaxf(m, mo);
        float c1 = __expf(m - M);
        float c2 = __expf(mo - M);
        sum = sum * c1 + so * c2;
        a0 = a0 * c1 + b0 * c2;
        a1 = a1 * c1 + b1 * c2;
        a2 = a2 * c1 + b2 * c2;
        a3 = a3 * c1 + b3 * c2;
        m = M;
    }

    if (slot == 0) {
        float inv = (sum > 0.0f) ? (1.0f / sum) : 0.0f;
        fvec4* op = (fvec4*)(agg + (size_t)node * 128 + h * 16);
        op[0] = a0 * inv;
        op[1] = a1 * inv;
        op[2] = a2 * inv;
        op[3] = a3 * inv;
    }
}

// ---------------------------------------------------------------------------
extern "C" void kernel_launch(void* const* d_in, const int* in_sizes, int n_in,
                              void* d_out, int out_size, void* d_ws, size_t ws_size,
                              hipStream_t stream) {
    const float* node = (const float*)d_in[0];
    const int*   ei   = (const int*)d_in[1];
    const float* ef   = (const float*)d_in[2];
    const float* Wq   = (const float*)d_in[3];
    const float* bq   = (const float*)d_in[4];
    const float* Wk   = (const float*)d_in[5];
    const float* bk   = (const float*)d_in[6];
    const float* Wv   = (const float*)d_in[7];
    const float* bv   = (const float*)d_in[8];
    const float* We   = (const float*)d_in[9];
    const float* be   = (const float*)d_in[10];
    const float* Wo   = (const float*)d_in[11];
    const float* bo   = (const float*)d_in[12];
    float* out = (float*)d_out;

    const int* row = ei;
    const int* col = ei + NEDGES;

    // workspace layout
    float* ws    = (float*)d_ws;
    float* Q     = ws;                                            // NNODES*128 f32
    unsigned short* KV = (unsigned short*)(Q + (size_t)NNODES * 128);  // NNODES*256 bf16
    float* ebias = (float*)(KV + (size_t)NNODES * 256);           // NEDGES*8 f32 (CSR order)
    float* agg   = ebias + (size_t)NEDGES * 8;                    // NNODES*128 f32
    int*   cnt      = (int*)(agg + (size_t)NNODES * 128);         // NNODES
    int*   offs     = cnt + NNODES;                               // NNODES+1
    int*   cursor   = offs + NNODES + 1;                          // NNODES
    int*   rank     = cursor + NNODES;                            // NEDGES
    int*   col_perm = rank + NEDGES;                              // NEDGES

    // CSR build (rebuilt every launch)
    zero_cnt<<<(NNODES + 255) / 256, 256, 0, stream>>>(cnt);
    hist_kernel<<<(NEDGES + 255) / 256, 256, 0, stream>>>(row, cnt);
    scan_kernel<<<1, 1024, 0, stream>>>(cnt, offs, cursor);
    scatter_kernel<<<(NEDGES + 255) / 256, 256, 0, stream>>>(row, col, cursor, rank, col_perm);

    dim3 gq((NNODES + TM - 1) / TM, DMODEL / TN);
    gemm128<false><<<gq, 256, 0, stream>>>(node, Wq, bq, Q,  NNODES, DMODEL, 128, 0);
    gemm128<true ><<<gq, 256, 0, stream>>>(node, Wk, bk, KV, NNODES, DMODEL, 256, 0);
    gemm128<true ><<<gq, 256, 0, stream>>>(node, Wv, bv, KV, NNODES, DMODEL, 256, 128);

    ef_bias_kernel<<<NEDGES * 8 / 256, 256, 0, stream>>>(ef, rank, We, be, ebias);

    fused_agg<<<(NNODES + 3) / 4, 256, 0, stream>>>(Q, KV, ebias, col_perm, offs, agg);

    gemm128<false><<<gq, 256, 0, stream>>>(agg, Wo, bo, out, NNODES, DMODEL, 128, 0);
}

// Round 9
// 454.316 us; speedup vs baseline: 3.8287x; 1.1117x over previous
//
#include <hip/hip_runtime.h>
#include <hip/hip_bf16.h>
#include <math.h>

#define NNODES 50000
#define NEDGES 800000
#define DMODEL 128
#define QK_SCALE 0.25f  // 1/sqrt(16)

typedef float fvec4 __attribute__((ext_vector_type(4)));
typedef short sv8  __attribute__((ext_vector_type(8)));   // 8 bf16 in 4 VGPRs

__device__ __forceinline__ unsigned short f2bf(float f) {
    unsigned int u = __float_as_uint(f);
    unsigned int r = (u + 0x7FFFu + ((u >> 16) & 1u)) >> 16;   // RNE
    return (unsigned short)r;
}

// convert 8 packed bf16 (one uint4) -> two fvec4 (memory order)
__device__ __forceinline__ void bf8_to_f32(uint4 u, fvec4& lo, fvec4& hi) {
    lo.x = __uint_as_float(u.x << 16); lo.y = __uint_as_float(u.x & 0xFFFF0000u);
    lo.z = __uint_as_float(u.y << 16); lo.w = __uint_as_float(u.y & 0xFFFF0000u);
    hi.x = __uint_as_float(u.z << 16); hi.y = __uint_as_float(u.z & 0xFFFF0000u);
    hi.z = __uint_as_float(u.w << 16); hi.w = __uint_as_float(u.w & 0xFFFF0000u);
}

// ---------------------------------------------------------------------------
// prep: node_features f32 -> Xb bf16 [N][128]; Wq/Wk/Wv f32 [k][n] ->
// Wb bf16 TRANSPOSED [w][n][k] (so MFMA B-frags read 16B-contiguous in k).
// ---------------------------------------------------------------------------
__global__ __launch_bounds__(256) void prep_kernel(const float* __restrict__ X,
                                                   const float* __restrict__ Wq,
                                                   const float* __restrict__ Wk,
                                                   const float* __restrict__ Wv,
                                                   unsigned short* __restrict__ Xb,
                                                   unsigned short* __restrict__ Wb) {
    int i = blockIdx.x * 256 + threadIdx.x;
    if (i < NNODES * 32) {                      // float4 granularity
        float4 v = *(const float4*)&X[(size_t)i * 4];
        ushort4 s;
        s.x = f2bf(v.x); s.y = f2bf(v.y); s.z = f2bf(v.z); s.w = f2bf(v.w);
        *(ushort4*)&Xb[(size_t)i * 4] = s;
    } else {
        int j = i - NNODES * 32;
        if (j < 3 * 16384) {
            int w = j >> 14, rem = j & 16383;
            int n = rem >> 7, k = rem & 127;
            const float* src = (w == 0) ? Wq : (w == 1) ? Wk : Wv;
            Wb[(size_t)w * 16384 + n * 128 + k] = f2bf(src[k * 128 + n]);
        }
    }
}

// ---------------------------------------------------------------------------
// QKV projection via bf16 MFMA, one dispatch (blockIdx.y = 0/1/2 -> Q/K/V).
// 64-row tile, 4 waves, N=128, K=128. A(16KB)+B(32KB) staged in LDS with
// XOR swizzle byte^=((row&7)<<4) on write AND read (reg-staged, rule #21).
// mfma_f32_16x16x32_bf16: A row=l&15,k=(l>>4)*8+j ; C/D col=l&15,row=(l>>4)*4+r.
// ---------------------------------------------------------------------------
__global__ __launch_bounds__(256) void gemm_qkv(const unsigned short* __restrict__ Xb,
                                                const unsigned short* __restrict__ Wb,
                                                const float* __restrict__ bq,
                                                const float* __restrict__ bk,
                                                const float* __restrict__ bv,
                                                unsigned short* __restrict__ Qb,
                                                unsigned short* __restrict__ KVb,
                                                int M) {
    __shared__ unsigned short Als[64 * 128];    // 16KB swizzled
    __shared__ unsigned short Bls[128 * 128];   // 32KB swizzled
    char* Ac = (char*)Als;
    char* Bc = (char*)Bls;

    int z = blockIdx.y;
    int r0 = blockIdx.x * 64;
    int tid = threadIdx.x;
    int wave = tid >> 6, lane = tid & 63;

    const char* Wsrc = (const char*)(Wb + (size_t)z * 16384);

    // stage A: 64 rows x 256B (clamped rows for the ragged last block)
    #pragma unroll
    for (int p = 0; p < 4; ++p) {
        int o = p * 4096 + tid * 16;
        int r = o >> 8;
        int gr = r0 + r; if (gr >= M) gr = M - 1;
        uint4 v = *(const uint4*)((const char*)Xb + (size_t)gr * 256 + (o & 255));
        *(uint4*)(Ac + r * 256 + ((o & 255) ^ ((r & 7) << 4))) = v;
    }
    // stage B: 128 rows (n) x 256B (k)
    #pragma unroll
    for (int p = 0; p < 8; ++p) {
        int o = p * 4096 + tid * 16;
        int r = o >> 8;
        uint4 v = *(const uint4*)(Wsrc + o);
        *(uint4*)(Bc + (o ^ ((r & 7) << 4))) = v;
    }
    __syncthreads();

    fvec4 acc[8] = {};
    int arow = wave * 16 + (lane & 15);
    int kchunk = (lane >> 4) * 16;              // byte offset of this lane's 8-k chunk

    #pragma unroll
    for (int ks = 0; ks < 4; ++ks) {
        int ain = (ks * 64 + kchunk) ^ ((arow & 7) << 4);
        sv8 af = *(const sv8*)(Ac + arow * 256 + ain);
        #pragma unroll
        for (int cf = 0; cf < 8; ++cf) {
            int brow = cf * 16 + (lane & 15);
            int bin = (ks * 64 + kchunk) ^ ((brow & 7) << 4);
            sv8 bf = *(const sv8*)(Bc + brow * 256 + bin);
            acc[cf] = __builtin_amdgcn_mfma_f32_16x16x32_bf16(af, bf, acc[cf], 0, 0, 0);
        }
    }

    unsigned short* dst; int ldc, coff; const float* bias;
    if (z == 0)      { dst = Qb;  ldc = 128; coff = 0;   bias = bq; }
    else if (z == 1) { dst = KVb; ldc = 256; coff = 0;   bias = bk; }
    else             { dst = KVb; ldc = 256; coff = 128; bias = bv; }

    #pragma unroll
    for (int cf = 0; cf < 8; ++cf) {
        int col = cf * 16 + (lane & 15);
        float b = bias[col];
        #pragma unroll
        for (int r = 0; r < 4; ++r) {
            int gr = r0 + wave * 16 + ((lane >> 4) * 4) + r;
            if (gr < M) dst[(size_t)gr * ldc + coff + col] = f2bf(acc[cf][r] + b);
        }
    }
}

// ---------------------------------------------------------------------------
// f32 SIMD GEMM (kept for the final output projection only)
// ---------------------------------------------------------------------------
#define TM 64
#define TN 64
#define TK 32
__global__ __launch_bounds__(256) void gemm128(const float* __restrict__ A,
                                               const float* __restrict__ W,
                                               const float* __restrict__ bias,
                                               float* __restrict__ C,
                                               int M, int N) {
    __shared__ float As[TK][TM + 4];
    __shared__ float Bs[TK][TN + 4];

    int tid = threadIdx.x;
    int bm = blockIdx.x * TM;
    int bn = blockIdx.y * TN;
    int ty = tid >> 4;
    int tx = tid & 15;

    float acc[4][4] = {};

    for (int k0 = 0; k0 < 128; k0 += TK) {
        #pragma unroll
        for (int i = 0; i < 2; ++i) {
            int idx = tid + i * 256;
            int row = idx >> 3;
            int c4  = idx & 7;
            int grow = bm + row;
            if (grow >= M) grow = M - 1;
            float4 v = *(const float4*)&A[(size_t)grow * 128 + k0 + c4 * 4];
            As[c4 * 4 + 0][row] = v.x;
            As[c4 * 4 + 1][row] = v.y;
            As[c4 * 4 + 2][row] = v.z;
            As[c4 * 4 + 3][row] = v.w;
        }
        #pragma unroll
        for (int i = 0; i < 2; ++i) {
            int idx = tid + i * 256;
            int row = idx >> 4;
            int c4  = idx & 15;
            float4 v = *(const float4*)&W[(size_t)(k0 + row) * N + bn + c4 * 4];
            *(float4*)&Bs[row][c4 * 4] = v;
        }
        __syncthreads();

        #pragma unroll
        for (int kk = 0; kk < TK; ++kk) {
            float4 a4 = *(const float4*)&As[kk][ty * 4];
            float4 b4 = *(const float4*)&Bs[kk][tx * 4];
            float av[4] = {a4.x, a4.y, a4.z, a4.w};
            float bv[4] = {b4.x, b4.y, b4.z, b4.w};
            #pragma unroll
            for (int i = 0; i < 4; ++i)
                #pragma unroll
                for (int j = 0; j < 4; ++j)
                    acc[i][j] += av[i] * bv[j];
        }
        __syncthreads();
    }

    float4 bvec = *(const float4*)&bias[bn + tx * 4];
    float bb[4] = {bvec.x, bvec.y, bvec.z, bvec.w};
    #pragma unroll
    for (int i = 0; i < 4; ++i) {
        int gr = bm + ty * 4 + i;
        if (gr < M) {
            float4 o;
            o.x = acc[i][0] + bb[0];
            o.y = acc[i][1] + bb[1];
            o.z = acc[i][2] + bb[2];
            o.w = acc[i][3] + bb[3];
            *(float4*)&C[(size_t)gr * N + bn + tx * 4] = o;
        }
    }
}

// ---------------------------------------------------------------------------
// CSR build: zero -> histogram -> scan -> scatter (emits rank & permuted col)
// ---------------------------------------------------------------------------
__global__ __launch_bounds__(256) void zero_cnt(int* __restrict__ cnt) {
    int i = blockIdx.x * 256 + threadIdx.x;
    if (i < NNODES) cnt[i] = 0;
}

__global__ __launch_bounds__(256) void hist_kernel(const int* __restrict__ row,
                                                   int* __restrict__ cnt) {
    int e = blockIdx.x * 256 + threadIdx.x;
    if (e < NEDGES) atomicAdd(&cnt[row[e]], 1);
}

__global__ __launch_bounds__(1024) void scan_kernel(const int* __restrict__ cnt,
                                                    int* __restrict__ offs,
                                                    int* __restrict__ cursor) {
    __shared__ int psum[1024];
    int tid = threadIdx.x;
    const int CH = (NNODES + 1023) / 1024;  // 49
    int base = tid * CH;
    int s = 0;
    for (int i = 0; i < CH; ++i) {
        int idx = base + i;
        if (idx < NNODES) s += cnt[idx];
    }
    psum[tid] = s;
    __syncthreads();
    for (int off = 1; off < 1024; off <<= 1) {
        int v = (tid >= off) ? psum[tid - off] : 0;
        __syncthreads();
        psum[tid] += v;
        __syncthreads();
    }
    int running = (tid == 0) ? 0 : psum[tid - 1];
    for (int i = 0; i < CH; ++i) {
        int idx = base + i;
        if (idx < NNODES) {
            offs[idx] = running;
            cursor[idx] = running;
            running += cnt[idx];
        }
    }
    if (tid == 0) offs[NNODES] = NEDGES;
}

__global__ __launch_bounds__(256) void scatter_kernel(const int* __restrict__ row,
                                                      const int* __restrict__ col,
                                                      int* __restrict__ cursor,
                                                      int* __restrict__ rank,
                                                      int* __restrict__ col_perm) {
    int e = blockIdx.x * 256 + threadIdx.x;
    if (e < NEDGES) {
        int pos = atomicAdd(&cursor[row[e]], 1);
        rank[e] = pos;
        col_perm[pos] = col[e];
    }
}

// ---------------------------------------------------------------------------
// ebias[pos,h] = ef[e,:] . We[:,h] + be[h]   written in CSR order (pos=rank[e])
// ---------------------------------------------------------------------------
__global__ __launch_bounds__(256) void ef_bias_kernel(const float* __restrict__ EF,
                                                      const int* __restrict__ rank,
                                                      const float* __restrict__ We,
                                                      const float* __restrict__ be,
                                                      float* __restrict__ ebias) {
    __shared__ float sWe[8][128];   // [h][d]
    __shared__ float sbe[8];
    for (int i = threadIdx.x; i < 1024; i += 256) {
        int d = i >> 3, h = i & 7;
        sWe[h][d] = We[i];          // We is [d][h] row-major
    }
    if (threadIdx.x < 8) sbe[threadIdx.x] = be[threadIdx.x];
    __syncthreads();

    int g = blockIdx.x * 256 + threadIdx.x;   // NEDGES*8 threads
    int e = g >> 3;
    int s = g & 7;
    if (e >= NEDGES) return;

    const fvec4* efv = (const fvec4*)(EF + (size_t)e * 128);
    float acc[8] = {0.f, 0.f, 0.f, 0.f, 0.f, 0.f, 0.f, 0.f};
    #pragma unroll
    for (int i = 0; i < 4; ++i) {
        int d4 = s + 8 * i;
        fvec4 v = __builtin_nontemporal_load(&efv[d4]);
        #pragma unroll
        for (int h = 0; h < 8; ++h) {
            fvec4 w = *(const fvec4*)&sWe[h][d4 * 4];
            acc[h] += v.x * w.x + v.y * w.y + v.z * w.z + v.w * w.w;
        }
    }

    #pragma unroll
    for (int off = 1; off < 8; off <<= 1)
        #pragma unroll
        for (int h = 0; h < 8; ++h)
            acc[h] += __shfl_xor(acc[h], off);

    int pos = rank[e];
    ebias[(size_t)pos * 8 + s] = acc[s] + sbe[s];
}

// ---------------------------------------------------------------------------
// fused QK^T + online segment softmax + PV, lane-local heads, bf16 Q & KV.
// wave = 1 node; lane = slot*8 + h.
// ---------------------------------------------------------------------------
__global__ __launch_bounds__(256) void fused_agg(const unsigned short* __restrict__ Qb,
                                                 const unsigned short* __restrict__ KV,
                                                 const float* __restrict__ ebias,
                                                 const int* __restrict__ col_perm,
                                                 const int* __restrict__ offs,
                                                 float* __restrict__ agg) {
    int node = blockIdx.x * 4 + (threadIdx.x >> 6);
    if (node >= NNODES) return;
    int lane = threadIdx.x & 63;
    int slot = lane >> 3;
    int h    = lane & 7;
    int start = offs[node];
    int end   = offs[node + 1];

    const uint4* qp = (const uint4*)(Qb + (size_t)node * 128 + h * 16);
    uint4 qu0 = qp[0], qu1 = qp[1];
    fvec4 q0, q1, q2, q3;
    bf8_to_f32(qu0, q0, q1);
    bf8_to_f32(qu1, q2, q3);

    float m = -3.0e38f;
    float sum = 0.0f;
    fvec4 a0 = {0.f,0.f,0.f,0.f}, a1 = {0.f,0.f,0.f,0.f};
    fvec4 a2 = {0.f,0.f,0.f,0.f}, a3 = {0.f,0.f,0.f,0.f};

    for (int i = start + slot; i < end; i += 8) {
        int c = col_perm[i];
        float eb = ebias[(size_t)i * 8 + h];
        const uint4* kp = (const uint4*)(KV + (size_t)c * 256 + h * 16);
        uint4 ku0 = kp[0],  ku1 = kp[1];
        uint4 vu0 = kp[16], vu1 = kp[17];      // V half: +128 elems = +16 uint4
        fvec4 k0, k1, k2, k3, v0, v1, v2, v3;
        bf8_to_f32(ku0, k0, k1);
        bf8_to_f32(ku1, k2, k3);
        bf8_to_f32(vu0, v0, v1);
        bf8_to_f32(vu1, v2, v3);

        fvec4 d4 = q0 * k0 + q1 * k1 + q2 * k2 + q3 * k3;
        float dot = d4.x + d4.y + d4.z + d4.w;

        float s = dot * QK_SCALE + eb;
        float mn = fmaxf(m, s);
        float corr = __expf(m - mn);
        float w = __expf(s - mn);
        sum = sum * corr + w;
        a0 = a0 * corr + w * v0;
        a1 = a1 * corr + w * v1;
        a2 = a2 * corr + w * v2;
        a3 = a3 * corr + w * v3;
        m = mn;
    }

    #pragma unroll
    for (int off = 8; off < 64; off <<= 1) {
        float mo = __shfl_xor(m, off);
        float so = __shfl_xor(sum, off);
        fvec4 b0, b1, b2, b3;
        b0.x = __shfl_xor(a0.x, off); b0.y = __shfl_xor(a0.y, off);
        b0.z = __shfl_xor(a0.z, off); b0.w = __shfl_xor(a0.w, off);
        b1.x = __shfl_xor(a1.x, off); b1.y = __shfl_xor(a1.y, off);
        b1.z = __shfl_xor(a1.z, off); b1.w = __shfl_xor(a1.w, off);
        b2.x = __shfl_xor(a2.x, off); b2.y = __shfl_xor(a2.y, off);
        b2.z = __shfl_xor(a2.z, off); b2.w = __shfl_xor(a2.w, off);
        b3.x = __shfl_xor(a3.x, off); b3.y = __shfl_xor(a3.y, off);
        b3.z = __shfl_xor(a3.z, off); b3.w = __shfl_xor(a3.w, off);
        float M = fmaxf(m, mo);
        float c1 = __expf(m - M);
        float c2 = __expf(mo - M);
        sum = sum * c1 + so * c2;
        a0 = a0 * c1 + b0 * c2;
        a1 = a1 * c1 + b1 * c2;
        a2 = a2 * c1 + b2 * c2;
        a3 = a3 * c1 + b3 * c2;
        m = M;
    }

    if (slot == 0) {
        float inv = (sum > 0.0f) ? (1.0f / sum) : 0.0f;
        fvec4* op = (fvec4*)(agg + (size_t)node * 128 + h * 16);
        op[0] = a0 * inv;
        op[1] = a1 * inv;
        op[2] = a2 * inv;
        op[3] = a3 * inv;
    }
}

// ---------------------------------------------------------------------------
extern "C" void kernel_launch(void* const* d_in, const int* in_sizes, int n_in,
                              void* d_out, int out_size, void* d_ws, size_t ws_size,
                              hipStream_t stream) {
    const float* node = (const float*)d_in[0];
    const int*   ei   = (const int*)d_in[1];
    const float* ef   = (const float*)d_in[2];
    const float* Wq   = (const float*)d_in[3];
    const float* bq   = (const float*)d_in[4];
    const float* Wk   = (const float*)d_in[5];
    const float* bk   = (const float*)d_in[6];
    const float* Wv   = (const float*)d_in[7];
    const float* bv   = (const float*)d_in[8];
    const float* We   = (const float*)d_in[9];
    const float* be   = (const float*)d_in[10];
    const float* Wo   = (const float*)d_in[11];
    const float* bo   = (const float*)d_in[12];
    float* out = (float*)d_out;

    const int* row = ei;
    const int* col = ei + NEDGES;

    // workspace layout
    unsigned short* Qb  = (unsigned short*)d_ws;                  // NNODES*128 bf16
    unsigned short* KVb = Qb + (size_t)NNODES * 128;              // NNODES*256 bf16
    unsigned short* Xb  = KVb + (size_t)NNODES * 256;             // NNODES*128 bf16
    unsigned short* Wb  = Xb + (size_t)NNODES * 128;              // 3*16384 bf16
    float* ebias = (float*)(Wb + 3 * 16384);                      // NEDGES*8 f32
    float* agg   = ebias + (size_t)NEDGES * 8;                    // NNODES*128 f32
    int*   cnt      = (int*)(agg + (size_t)NNODES * 128);         // NNODES
    int*   offs     = cnt + NNODES;                               // NNODES+1
    int*   cursor   = offs + NNODES + 1;                          // NNODES
    int*   rank     = cursor + NNODES;                            // NEDGES
    int*   col_perm = rank + NEDGES;                              // NEDGES

    // bf16 precompute + CSR build (all rebuilt every launch)
    prep_kernel<<<(NNODES * 32 + 3 * 16384 + 255) / 256, 256, 0, stream>>>(node, Wq, Wk, Wv, Xb, Wb);
    zero_cnt<<<(NNODES + 255) / 256, 256, 0, stream>>>(cnt);
    hist_kernel<<<(NEDGES + 255) / 256, 256, 0, stream>>>(row, cnt);
    scan_kernel<<<1, 1024, 0, stream>>>(cnt, offs, cursor);
    scatter_kernel<<<(NEDGES + 255) / 256, 256, 0, stream>>>(row, col, cursor, rank, col_perm);

    dim3 gqkv((NNODES + 63) / 64, 3);
    gemm_qkv<<<gqkv, 256, 0, stream>>>(Xb, Wb, bq, bk, bv, Qb, KVb, NNODES);

    ef_bias_kernel<<<NEDGES * 8 / 256, 256, 0, stream>>>(ef, rank, We, be, ebias);

    fused_agg<<<(NNODES + 3) / 4, 256, 0, stream>>>(Qb, KVb, ebias, col_perm, offs, agg);

    dim3 go((NNODES + TM - 1) / TM, DMODEL / TN);
    gemm128<<<go, 256, 0, stream>>>(agg, Wo, bo, out, NNODES, DMODEL);
}

// Round 10
// 448.117 us; speedup vs baseline: 3.8817x; 1.0138x over previous
//
#include <hip/hip_runtime.h>
#include <hip/hip_bf16.h>
#include <math.h>

#define NNODES 50000
#define NEDGES 800000
#define DMODEL 128
#define QK_SCALE 0.25f  // 1/sqrt(16)

typedef float fvec4 __attribute__((ext_vector_type(4)));
typedef short sv8  __attribute__((ext_vector_type(8)));   // 8 bf16 in 4 VGPRs

__device__ __forceinline__ unsigned short f2bf(float f) {
    unsigned int u = __float_as_uint(f);
    unsigned int r = (u + 0x7FFFu + ((u >> 16) & 1u)) >> 16;   // RNE
    return (unsigned short)r;
}

// convert 8 packed bf16 (one uint4) -> two fvec4 (memory order)
__device__ __forceinline__ void bf8_to_f32(uint4 u, fvec4& lo, fvec4& hi) {
    lo.x = __uint_as_float(u.x << 16); lo.y = __uint_as_float(u.x & 0xFFFF0000u);
    lo.z = __uint_as_float(u.y << 16); lo.w = __uint_as_float(u.y & 0xFFFF0000u);
    hi.x = __uint_as_float(u.z << 16); hi.y = __uint_as_float(u.z & 0xFFFF0000u);
    hi.z = __uint_as_float(u.w << 16); hi.w = __uint_as_float(u.w & 0xFFFF0000u);
}

// ---------------------------------------------------------------------------
// prep: X f32 -> Xb bf16; Wq/Wk/Wv/Wo f32 [k][n] -> Wb bf16 TRANSPOSED
// [w][n][k]; also zeroes cnt (fused zero_cnt).
// ---------------------------------------------------------------------------
__global__ __launch_bounds__(256) void prep_kernel(const float* __restrict__ X,
                                                   const float* __restrict__ Wq,
                                                   const float* __restrict__ Wk,
                                                   const float* __restrict__ Wv,
                                                   const float* __restrict__ Wo,
                                                   unsigned short* __restrict__ Xb,
                                                   unsigned short* __restrict__ Wb,
                                                   int* __restrict__ cnt) {
    int i = blockIdx.x * 256 + threadIdx.x;
    if (i < NNODES * 32) {                      // float4 granularity
        float4 v = *(const float4*)&X[(size_t)i * 4];
        ushort4 s;
        s.x = f2bf(v.x); s.y = f2bf(v.y); s.z = f2bf(v.z); s.w = f2bf(v.w);
        *(ushort4*)&Xb[(size_t)i * 4] = s;
    } else {
        int j = i - NNODES * 32;
        if (j < 4 * 16384) {
            int w = j >> 14, rem = j & 16383;
            int n = rem >> 7, k = rem & 127;
            const float* src = (w == 0) ? Wq : (w == 1) ? Wk : (w == 2) ? Wv : Wo;
            Wb[j] = f2bf(src[k * 128 + n]);
        } else {
            int c = j - 4 * 16384;
            if (c < NNODES) cnt[c] = 0;
        }
    }
}

// ---------------------------------------------------------------------------
// QKV projection via bf16 MFMA, one dispatch (blockIdx.y = 0/1/2 -> Q/K/V).
// 64-row tile, 4 waves. A(16KB)+B(32KB) in LDS, XOR swizzle on write AND read.
// ---------------------------------------------------------------------------
__global__ __launch_bounds__(256) void gemm_qkv(const unsigned short* __restrict__ Xb,
                                                const unsigned short* __restrict__ Wb,
                                                const float* __restrict__ bq,
                                                const float* __restrict__ bk,
                                                const float* __restrict__ bv,
                                                unsigned short* __restrict__ Qb,
                                                unsigned short* __restrict__ KVb,
                                                int M) {
    __shared__ unsigned short Als[64 * 128];
    __shared__ unsigned short Bls[128 * 128];
    char* Ac = (char*)Als;
    char* Bc = (char*)Bls;

    int z = blockIdx.y;
    int r0 = blockIdx.x * 64;
    int tid = threadIdx.x;
    int wave = tid >> 6, lane = tid & 63;

    const char* Wsrc = (const char*)(Wb + (size_t)z * 16384);

    #pragma unroll
    for (int p = 0; p < 4; ++p) {
        int o = p * 4096 + tid * 16;
        int r = o >> 8;
        int gr = r0 + r; if (gr >= M) gr = M - 1;
        uint4 v = *(const uint4*)((const char*)Xb + (size_t)gr * 256 + (o & 255));
        *(uint4*)(Ac + r * 256 + ((o & 255) ^ ((r & 7) << 4))) = v;
    }
    #pragma unroll
    for (int p = 0; p < 8; ++p) {
        int o = p * 4096 + tid * 16;
        int r = o >> 8;
        uint4 v = *(const uint4*)(Wsrc + o);
        *(uint4*)(Bc + (o ^ ((r & 7) << 4))) = v;
    }
    __syncthreads();

    fvec4 acc[8] = {};
    int arow = wave * 16 + (lane & 15);
    int kchunk = (lane >> 4) * 16;

    #pragma unroll
    for (int ks = 0; ks < 4; ++ks) {
        int ain = (ks * 64 + kchunk) ^ ((arow & 7) << 4);
        sv8 af = *(const sv8*)(Ac + arow * 256 + ain);
        #pragma unroll
        for (int cf = 0; cf < 8; ++cf) {
            int brow = cf * 16 + (lane & 15);
            int bin = (ks * 64 + kchunk) ^ ((brow & 7) << 4);
            sv8 bf = *(const sv8*)(Bc + brow * 256 + bin);
            acc[cf] = __builtin_amdgcn_mfma_f32_16x16x32_bf16(af, bf, acc[cf], 0, 0, 0);
        }
    }

    unsigned short* dst; int ldc, coff; const float* bias;
    if (z == 0)      { dst = Qb;  ldc = 128; coff = 0;   bias = bq; }
    else if (z == 1) { dst = KVb; ldc = 256; coff = 0;   bias = bk; }
    else             { dst = KVb; ldc = 256; coff = 128; bias = bv; }

    #pragma unroll
    for (int cf = 0; cf < 8; ++cf) {
        int col = cf * 16 + (lane & 15);
        float b = bias[col];
        #pragma unroll
        for (int r = 0; r < 4; ++r) {
            int gr = r0 + wave * 16 + ((lane >> 4) * 4) + r;
            if (gr < M) dst[(size_t)gr * ldc + coff + col] = f2bf(acc[cf][r] + b);
        }
    }
}

// ---------------------------------------------------------------------------
// output projection via bf16 MFMA: out f32 = aggb bf16 @ Wo^T bf16 + bo
// ---------------------------------------------------------------------------
__global__ __launch_bounds__(256) void gemm_out(const unsigned short* __restrict__ Ab,
                                                const unsigned short* __restrict__ Wob,
                                                const float* __restrict__ bo,
                                                float* __restrict__ outp, int M) {
    __shared__ unsigned short Als[64 * 128];
    __shared__ unsigned short Bls[128 * 128];
    char* Ac = (char*)Als;
    char* Bc = (char*)Bls;

    int r0 = blockIdx.x * 64;
    int tid = threadIdx.x;
    int wave = tid >> 6, lane = tid & 63;

    #pragma unroll
    for (int p = 0; p < 4; ++p) {
        int o = p * 4096 + tid * 16;
        int r = o >> 8;
        int gr = r0 + r; if (gr >= M) gr = M - 1;
        uint4 v = *(const uint4*)((const char*)Ab + (size_t)gr * 256 + (o & 255));
        *(uint4*)(Ac + r * 256 + ((o & 255) ^ ((r & 7) << 4))) = v;
    }
    #pragma unroll
    for (int p = 0; p < 8; ++p) {
        int o = p * 4096 + tid * 16;
        int r = o >> 8;
        uint4 v = *(const uint4*)((const char*)Wob + o);
        *(uint4*)(Bc + (o ^ ((r & 7) << 4))) = v;
    }
    __syncthreads();

    fvec4 acc[8] = {};
    int arow = wave * 16 + (lane & 15);
    int kchunk = (lane >> 4) * 16;

    #pragma unroll
    for (int ks = 0; ks < 4; ++ks) {
        int ain = (ks * 64 + kchunk) ^ ((arow & 7) << 4);
        sv8 af = *(const sv8*)(Ac + arow * 256 + ain);
        #pragma unroll
        for (int cf = 0; cf < 8; ++cf) {
            int brow = cf * 16 + (lane & 15);
            int bin = (ks * 64 + kchunk) ^ ((brow & 7) << 4);
            sv8 bf = *(const sv8*)(Bc + brow * 256 + bin);
            acc[cf] = __builtin_amdgcn_mfma_f32_16x16x32_bf16(af, bf, acc[cf], 0, 0, 0);
        }
    }

    #pragma unroll
    for (int cf = 0; cf < 8; ++cf) {
        int col = cf * 16 + (lane & 15);
        float b = bo[col];
        #pragma unroll
        for (int r = 0; r < 4; ++r) {
            int gr = r0 + wave * 16 + ((lane >> 4) * 4) + r;
            if (gr < M) outp[(size_t)gr * 128 + col] = acc[cf][r] + b;
        }
    }
}

// ---------------------------------------------------------------------------
// CSR build: histogram -> scan -> scatter (emits rank & permuted col)
// ---------------------------------------------------------------------------
__global__ __launch_bounds__(256) void hist_kernel(const int* __restrict__ row,
                                                   int* __restrict__ cnt) {
    int e = blockIdx.x * 256 + threadIdx.x;
    if (e < NEDGES) atomicAdd(&cnt[row[e]], 1);
}

__global__ __launch_bounds__(1024) void scan_kernel(const int* __restrict__ cnt,
                                                    int* __restrict__ offs,
                                                    int* __restrict__ cursor) {
    __shared__ int psum[1024];
    int tid = threadIdx.x;
    const int CH = (NNODES + 1023) / 1024;  // 49
    int base = tid * CH;
    int s = 0;
    for (int i = 0; i < CH; ++i) {
        int idx = base + i;
        if (idx < NNODES) s += cnt[idx];
    }
    psum[tid] = s;
    __syncthreads();
    for (int off = 1; off < 1024; off <<= 1) {
        int v = (tid >= off) ? psum[tid - off] : 0;
        __syncthreads();
        psum[tid] += v;
        __syncthreads();
    }
    int running = (tid == 0) ? 0 : psum[tid - 1];
    for (int i = 0; i < CH; ++i) {
        int idx = base + i;
        if (idx < NNODES) {
            offs[idx] = running;
            cursor[idx] = running;
            running += cnt[idx];
        }
    }
    if (tid == 0) offs[NNODES] = NEDGES;
}

__global__ __launch_bounds__(256) void scatter_kernel(const int* __restrict__ row,
                                                      const int* __restrict__ col,
                                                      int* __restrict__ cursor,
                                                      int* __restrict__ rank,
                                                      int* __restrict__ col_perm) {
    int e = blockIdx.x * 256 + threadIdx.x;
    if (e < NEDGES) {
        int pos = atomicAdd(&cursor[row[e]], 1);
        rank[e] = pos;
        col_perm[pos] = col[e];
    }
}

// ---------------------------------------------------------------------------
// ebias[pos,h] = bf16( ef[e,:] . We[:,h] + be[h] )   (CSR order, pos=rank[e])
// ---------------------------------------------------------------------------
__global__ __launch_bounds__(256) void ef_bias_kernel(const float* __restrict__ EF,
                                                      const int* __restrict__ rank,
                                                      const float* __restrict__ We,
                                                      const float* __restrict__ be,
                                                      unsigned short* __restrict__ ebias) {
    __shared__ float sWe[8][128];   // [h][d]
    __shared__ float sbe[8];
    for (int i = threadIdx.x; i < 1024; i += 256) {
        int d = i >> 3, h = i & 7;
        sWe[h][d] = We[i];          // We is [d][h] row-major
    }
    if (threadIdx.x < 8) sbe[threadIdx.x] = be[threadIdx.x];
    __syncthreads();

    int g = blockIdx.x * 256 + threadIdx.x;   // NEDGES*8 threads
    int e = g >> 3;
    int s = g & 7;
    if (e >= NEDGES) return;

    const fvec4* efv = (const fvec4*)(EF + (size_t)e * 128);
    float acc[8] = {0.f, 0.f, 0.f, 0.f, 0.f, 0.f, 0.f, 0.f};
    #pragma unroll
    for (int i = 0; i < 4; ++i) {
        int d4 = s + 8 * i;
        fvec4 v = __builtin_nontemporal_load(&efv[d4]);
        #pragma unroll
        for (int h = 0; h < 8; ++h) {
            fvec4 w = *(const fvec4*)&sWe[h][d4 * 4];
            acc[h] += v.x * w.x + v.y * w.y + v.z * w.z + v.w * w.w;
        }
    }

    #pragma unroll
    for (int off = 1; off < 8; off <<= 1)
        #pragma unroll
        for (int h = 0; h < 8; ++h)
            acc[h] += __shfl_xor(acc[h], off);

    int pos = rank[e];
    ebias[(size_t)pos * 8 + s] = f2bf(acc[s] + sbe[s]);
}

// ---------------------------------------------------------------------------
// fused QK^T + online segment softmax + PV; bf16 Q/KV/ebias, bf16 agg out.
// wave = 1 node; lane = slot*8 + h.
// ---------------------------------------------------------------------------
__global__ __launch_bounds__(256) void fused_agg(const unsigned short* __restrict__ Qb,
                                                 const unsigned short* __restrict__ KV,
                                                 const unsigned short* __restrict__ ebias,
                                                 const int* __restrict__ col_perm,
                                                 const int* __restrict__ offs,
                                                 unsigned short* __restrict__ aggb) {
    int node = blockIdx.x * 4 + (threadIdx.x >> 6);
    if (node >= NNODES) return;
    int lane = threadIdx.x & 63;
    int slot = lane >> 3;
    int h    = lane & 7;
    int start = offs[node];
    int end   = offs[node + 1];

    const uint4* qp = (const uint4*)(Qb + (size_t)node * 128 + h * 16);
    uint4 qu0 = qp[0], qu1 = qp[1];
    fvec4 q0, q1, q2, q3;
    bf8_to_f32(qu0, q0, q1);
    bf8_to_f32(qu1, q2, q3);

    float m = -3.0e38f;
    float sum = 0.0f;
    fvec4 a0 = {0.f,0.f,0.f,0.f}, a1 = {0.f,0.f,0.f,0.f};
    fvec4 a2 = {0.f,0.f,0.f,0.f}, a3 = {0.f,0.f,0.f,0.f};

    for (int i = start + slot; i < end; i += 8) {
        int c = col_perm[i];
        float eb = __uint_as_float(((unsigned int)ebias[(size_t)i * 8 + h]) << 16);
        const uint4* kp = (const uint4*)(KV + (size_t)c * 256 + h * 16);
        uint4 ku0 = kp[0],  ku1 = kp[1];
        uint4 vu0 = kp[16], vu1 = kp[17];      // V half: +128 elems = +16 uint4
        fvec4 k0, k1, k2, k3, v0, v1, v2, v3;
        bf8_to_f32(ku0, k0, k1);
        bf8_to_f32(ku1, k2, k3);
        bf8_to_f32(vu0, v0, v1);
        bf8_to_f32(vu1, v2, v3);

        fvec4 d4 = q0 * k0 + q1 * k1 + q2 * k2 + q3 * k3;
        float dot = d4.x + d4.y + d4.z + d4.w;

        float s = dot * QK_SCALE + eb;
        float mn = fmaxf(m, s);
        float corr = __expf(m - mn);
        float w = __expf(s - mn);
        sum = sum * corr + w;
        a0 = a0 * corr + w * v0;
        a1 = a1 * corr + w * v1;
        a2 = a2 * corr + w * v2;
        a3 = a3 * corr + w * v3;
        m = mn;
    }

    #pragma unroll
    for (int off = 8; off < 64; off <<= 1) {
        float mo = __shfl_xor(m, off);
        float so = __shfl_xor(sum, off);
        fvec4 b0, b1, b2, b3;
        b0.x = __shfl_xor(a0.x, off); b0.y = __shfl_xor(a0.y, off);
        b0.z = __shfl_xor(a0.z, off); b0.w = __shfl_xor(a0.w, off);
        b1.x = __shfl_xor(a1.x, off); b1.y = __shfl_xor(a1.y, off);
        b1.z = __shfl_xor(a1.z, off); b1.w = __shfl_xor(a1.w, off);
        b2.x = __shfl_xor(a2.x, off); b2.y = __shfl_xor(a2.y, off);
        b2.z = __shfl_xor(a2.z, off); b2.w = __shfl_xor(a2.w, off);
        b3.x = __shfl_xor(a3.x, off); b3.y = __shfl_xor(a3.y, off);
        b3.z = __shfl_xor(a3.z, off); b3.w = __shfl_xor(a3.w, off);
        float M = fmaxf(m, mo);
        float c1 = __expf(m - M);
        float c2 = __expf(mo - M);
        sum = sum * c1 + so * c2;
        a0 = a0 * c1 + b0 * c2;
        a1 = a1 * c1 + b1 * c2;
        a2 = a2 * c1 + b2 * c2;
        a3 = a3 * c1 + b3 * c2;
        m = M;
    }

    if (slot == 0) {
        float inv = (sum > 0.0f) ? (1.0f / sum) : 0.0f;
        unsigned short* op = aggb + (size_t)node * 128 + h * 16;
        ushort4 s;
        s.x = f2bf(a0.x * inv); s.y = f2bf(a0.y * inv); s.z = f2bf(a0.z * inv); s.w = f2bf(a0.w * inv);
        *(ushort4*)(op + 0) = s;
        s.x = f2bf(a1.x * inv); s.y = f2bf(a1.y * inv); s.z = f2bf(a1.z * inv); s.w = f2bf(a1.w * inv);
        *(ushort4*)(op + 4) = s;
        s.x = f2bf(a2.x * inv); s.y = f2bf(a2.y * inv); s.z = f2bf(a2.z * inv); s.w = f2bf(a2.w * inv);
        *(ushort4*)(op + 8) = s;
        s.x = f2bf(a3.x * inv); s.y = f2bf(a3.y * inv); s.z = f2bf(a3.z * inv); s.w = f2bf(a3.w * inv);
        *(ushort4*)(op + 12) = s;
    }
}

// ---------------------------------------------------------------------------
extern "C" void kernel_launch(void* const* d_in, const int* in_sizes, int n_in,
                              void* d_out, int out_size, void* d_ws, size_t ws_size,
                              hipStream_t stream) {
    const float* node = (const float*)d_in[0];
    const int*   ei   = (const int*)d_in[1];
    const float* ef   = (const float*)d_in[2];
    const float* Wq   = (const float*)d_in[3];
    const float* bq   = (const float*)d_in[4];
    const float* Wk   = (const float*)d_in[5];
    const float* bk   = (const float*)d_in[6];
    const float* Wv   = (const float*)d_in[7];
    const float* bv   = (const float*)d_in[8];
    const float* We   = (const float*)d_in[9];
    const float* be   = (const float*)d_in[10];
    const float* Wo   = (const float*)d_in[11];
    const float* bo   = (const float*)d_in[12];
    float* out = (float*)d_out;

    const int* row = ei;
    const int* col = ei + NEDGES;

    // workspace layout (all 16B-aligned; verified offsets)
    unsigned short* Qb   = (unsigned short*)d_ws;                 // NNODES*128 bf16
    unsigned short* KVb  = Qb  + (size_t)NNODES * 128;            // NNODES*256 bf16
    unsigned short* Xb   = KVb + (size_t)NNODES * 256;            // NNODES*128 bf16
    unsigned short* Wb   = Xb  + (size_t)NNODES * 128;            // 4*16384 bf16 (Wq,Wk,Wv,Wo transposed)
    unsigned short* aggb = Wb  + 4 * 16384;                       // NNODES*128 bf16
    unsigned short* ebb  = aggb + (size_t)NNODES * 128;           // NEDGES*8 bf16 (CSR order)
    int*   cnt      = (int*)(ebb + (size_t)NEDGES * 8);           // NNODES
    int*   offs     = cnt + NNODES;                               // NNODES+1
    int*   cursor   = offs + NNODES + 1;                          // NNODES
    int*   rank     = cursor + NNODES;                            // NEDGES
    int*   col_perm = rank + NEDGES;                              // NEDGES

    // prep (bf16 converts + W transposes + cnt zero) + CSR build
    prep_kernel<<<(NNODES * 32 + 4 * 16384 + NNODES + 255) / 256, 256, 0, stream>>>(
        node, Wq, Wk, Wv, Wo, Xb, Wb, cnt);
    hist_kernel<<<(NEDGES + 255) / 256, 256, 0, stream>>>(row, cnt);
    scan_kernel<<<1, 1024, 0, stream>>>(cnt, offs, cursor);
    scatter_kernel<<<(NEDGES + 255) / 256, 256, 0, stream>>>(row, col, cursor, rank, col_perm);

    dim3 gqkv((NNODES + 63) / 64, 3);
    gemm_qkv<<<gqkv, 256, 0, stream>>>(Xb, Wb, bq, bk, bv, Qb, KVb, NNODES);

    ef_bias_kernel<<<NEDGES * 8 / 256, 256, 0, stream>>>(ef, rank, We, be, ebb);

    fused_agg<<<(NNODES + 3) / 4, 256, 0, stream>>>(Qb, KVb, ebb, col_perm, offs, aggb);

    gemm_out<<<(NNODES + 63) / 64, 256, 0, stream>>>(aggb, Wb + 3 * 16384, bo, out, NNODES);
}

// Round 11
// 336.336 us; speedup vs baseline: 5.1718x; 1.3324x over previous
//
#include <hip/hip_runtime.h>
#include <hip/hip_bf16.h>
#include <math.h>

#define NNODES 50000
#define NEDGES 800000
#define DMODEL 128
#define QK_SCALE 0.25f  // 1/sqrt(16)
#define NSB 196         // scan blocks = ceil(NNODES/256)

typedef float fvec4 __attribute__((ext_vector_type(4)));
typedef short sv8  __attribute__((ext_vector_type(8)));   // 8 bf16 in 4 VGPRs

__device__ __forceinline__ unsigned short f2bf(float f) {
    unsigned int u = __float_as_uint(f);
    unsigned int r = (u + 0x7FFFu + ((u >> 16) & 1u)) >> 16;   // RNE
    return (unsigned short)r;
}

// convert 8 packed bf16 (one uint4) -> two fvec4 (memory order)
__device__ __forceinline__ void bf8_to_f32(uint4 u, fvec4& lo, fvec4& hi) {
    lo.x = __uint_as_float(u.x << 16); lo.y = __uint_as_float(u.x & 0xFFFF0000u);
    lo.z = __uint_as_float(u.y << 16); lo.w = __uint_as_float(u.y & 0xFFFF0000u);
    hi.x = __uint_as_float(u.z << 16); hi.y = __uint_as_float(u.z & 0xFFFF0000u);
    hi.z = __uint_as_float(u.w << 16); hi.w = __uint_as_float(u.w & 0xFFFF0000u);
}

// ---------------------------------------------------------------------------
// prep: X f32 -> Xb bf16; Wq/Wk/Wv/Wo f32 [k][n] -> Wb bf16 TRANSPOSED
// [w][n][k]; also zeroes cnt.
// ---------------------------------------------------------------------------
__global__ __launch_bounds__(256) void prep_kernel(const float* __restrict__ X,
                                                   const float* __restrict__ Wq,
                                                   const float* __restrict__ Wk,
                                                   const float* __restrict__ Wv,
                                                   const float* __restrict__ Wo,
                                                   unsigned short* __restrict__ Xb,
                                                   unsigned short* __restrict__ Wb,
                                                   int* __restrict__ cnt) {
    int i = blockIdx.x * 256 + threadIdx.x;
    if (i < NNODES * 32) {                      // float4 granularity
        float4 v = *(const float4*)&X[(size_t)i * 4];
        ushort4 s;
        s.x = f2bf(v.x); s.y = f2bf(v.y); s.z = f2bf(v.z); s.w = f2bf(v.w);
        *(ushort4*)&Xb[(size_t)i * 4] = s;
    } else {
        int j = i - NNODES * 32;
        if (j < 4 * 16384) {
            int w = j >> 14, rem = j & 16383;
            int n = rem >> 7, k = rem & 127;
            const float* src = (w == 0) ? Wq : (w == 1) ? Wk : (w == 2) ? Wv : Wo;
            Wb[j] = f2bf(src[k * 128 + n]);
        } else {
            int c = j - 4 * 16384;
            if (c < NNODES) cnt[c] = 0;
        }
    }
}

// ---------------------------------------------------------------------------
// QKV projection via bf16 MFMA (blockIdx.y = 0/1/2 -> Q/K/V).
// K/V epilogue writes PART-INTERLEAVED rows:
//   KV[c][256] = [Kp0: h0..h7 x8][Kp1: h0..h7 x8][Vp0][Vp1]
//   elem(col) = coff + ((col&8)<<3) + ((col>>4)<<3) + (col&7)
// so fused_agg's per-h 16B reads are CONTIGUOUS across the 8 head-lanes
// (2 cache lines per slot per instruction = TA minimum).
// ---------------------------------------------------------------------------
__global__ __launch_bounds__(256) void gemm_qkv(const unsigned short* __restrict__ Xb,
                                                const unsigned short* __restrict__ Wb,
                                                const float* __restrict__ bq,
                                                const float* __restrict__ bk,
                                                const float* __restrict__ bv,
                                                unsigned short* __restrict__ Qb,
                                                unsigned short* __restrict__ KVb,
                                                int M) {
    __shared__ unsigned short Als[64 * 128];
    __shared__ unsigned short Bls[128 * 128];
    char* Ac = (char*)Als;
    char* Bc = (char*)Bls;

    int z = blockIdx.y;
    int r0 = blockIdx.x * 64;
    int tid = threadIdx.x;
    int wave = tid >> 6, lane = tid & 63;

    const char* Wsrc = (const char*)(Wb + (size_t)z * 16384);

    #pragma unroll
    for (int p = 0; p < 4; ++p) {
        int o = p * 4096 + tid * 16;
        int r = o >> 8;
        int gr = r0 + r; if (gr >= M) gr = M - 1;
        uint4 v = *(const uint4*)((const char*)Xb + (size_t)gr * 256 + (o & 255));
        *(uint4*)(Ac + r * 256 + ((o & 255) ^ ((r & 7) << 4))) = v;
    }
    #pragma unroll
    for (int p = 0; p < 8; ++p) {
        int o = p * 4096 + tid * 16;
        int r = o >> 8;
        uint4 v = *(const uint4*)(Wsrc + o);
        *(uint4*)(Bc + (o ^ ((r & 7) << 4))) = v;
    }
    __syncthreads();

    fvec4 acc[8] = {};
    int arow = wave * 16 + (lane & 15);
    int kchunk = (lane >> 4) * 16;

    #pragma unroll
    for (int ks = 0; ks < 4; ++ks) {
        int ain = (ks * 64 + kchunk) ^ ((arow & 7) << 4);
        sv8 af = *(const sv8*)(Ac + arow * 256 + ain);
        #pragma unroll
        for (int cf = 0; cf < 8; ++cf) {
            int brow = cf * 16 + (lane & 15);
            int bin = (ks * 64 + kchunk) ^ ((brow & 7) << 4);
            sv8 bf = *(const sv8*)(Bc + brow * 256 + bin);
            acc[cf] = __builtin_amdgcn_mfma_f32_16x16x32_bf16(af, bf, acc[cf], 0, 0, 0);
        }
    }

    const float* bias = (z == 0) ? bq : (z == 1) ? bk : bv;

    #pragma unroll
    for (int cf = 0; cf < 8; ++cf) {
        int col = cf * 16 + (lane & 15);
        float b = bias[col];
        #pragma unroll
        for (int r = 0; r < 4; ++r) {
            int gr = r0 + wave * 16 + ((lane >> 4) * 4) + r;
            if (gr < M) {
                unsigned short val = f2bf(acc[cf][r] + b);
                if (z == 0) {
                    Qb[(size_t)gr * 128 + col] = val;
                } else {
                    int coff = (z == 1) ? 0 : 128;
                    int off = coff + ((col & 8) << 3) + ((col >> 4) << 3) + (col & 7);
                    KVb[(size_t)gr * 256 + off] = val;
                }
            }
        }
    }
}

// ---------------------------------------------------------------------------
// output projection via bf16 MFMA: out f32 = aggb bf16 @ Wo^T bf16 + bo
// ---------------------------------------------------------------------------
__global__ __launch_bounds__(256) void gemm_out(const unsigned short* __restrict__ Ab,
                                                const unsigned short* __restrict__ Wob,
                                                const float* __restrict__ bo,
                                                float* __restrict__ outp, int M) {
    __shared__ unsigned short Als[64 * 128];
    __shared__ unsigned short Bls[128 * 128];
    char* Ac = (char*)Als;
    char* Bc = (char*)Bls;

    int r0 = blockIdx.x * 64;
    int tid = threadIdx.x;
    int wave = tid >> 6, lane = tid & 63;

    #pragma unroll
    for (int p = 0; p < 4; ++p) {
        int o = p * 4096 + tid * 16;
        int r = o >> 8;
        int gr = r0 + r; if (gr >= M) gr = M - 1;
        uint4 v = *(const uint4*)((const char*)Ab + (size_t)gr * 256 + (o & 255));
        *(uint4*)(Ac + r * 256 + ((o & 255) ^ ((r & 7) << 4))) = v;
    }
    #pragma unroll
    for (int p = 0; p < 8; ++p) {
        int o = p * 4096 + tid * 16;
        int r = o >> 8;
        uint4 v = *(const uint4*)((const char*)Wob + o);
        *(uint4*)(Bc + (o ^ ((r & 7) << 4))) = v;
    }
    __syncthreads();

    fvec4 acc[8] = {};
    int arow = wave * 16 + (lane & 15);
    int kchunk = (lane >> 4) * 16;

    #pragma unroll
    for (int ks = 0; ks < 4; ++ks) {
        int ain = (ks * 64 + kchunk) ^ ((arow & 7) << 4);
        sv8 af = *(const sv8*)(Ac + arow * 256 + ain);
        #pragma unroll
        for (int cf = 0; cf < 8; ++cf) {
            int brow = cf * 16 + (lane & 15);
            int bin = (ks * 64 + kchunk) ^ ((brow & 7) << 4);
            sv8 bf = *(const sv8*)(Bc + brow * 256 + bin);
            acc[cf] = __builtin_amdgcn_mfma_f32_16x16x32_bf16(af, bf, acc[cf], 0, 0, 0);
        }
    }

    #pragma unroll
    for (int cf = 0; cf < 8; ++cf) {
        int col = cf * 16 + (lane & 15);
        float b = bo[col];
        #pragma unroll
        for (int r = 0; r < 4; ++r) {
            int gr = r0 + wave * 16 + ((lane >> 4) * 4) + r;
            if (gr < M) outp[(size_t)gr * 128 + col] = acc[cf][r] + b;
        }
    }
}

// ---------------------------------------------------------------------------
// CSR build: histogram -> 3-phase parallel scan -> scatter
// ---------------------------------------------------------------------------
__global__ __launch_bounds__(256) void hist_kernel(const int* __restrict__ row,
                                                   int* __restrict__ cnt) {
    int e = blockIdx.x * 256 + threadIdx.x;
    if (e < NEDGES) atomicAdd(&cnt[row[e]], 1);
}

__global__ __launch_bounds__(256) void scan1_kernel(const int* __restrict__ cnt,
                                                    int* __restrict__ bsum) {
    __shared__ int red[256];
    int idx = blockIdx.x * 256 + threadIdx.x;
    red[threadIdx.x] = (idx < NNODES) ? cnt[idx] : 0;
    __syncthreads();
    for (int off = 128; off > 0; off >>= 1) {
        if (threadIdx.x < off) red[threadIdx.x] += red[threadIdx.x + off];
        __syncthreads();
    }
    if (threadIdx.x == 0) bsum[blockIdx.x] = red[0];
}

__global__ __launch_bounds__(256) void scan2_kernel(const int* __restrict__ bsum,
                                                    int* __restrict__ bpre) {
    __shared__ int ps[256];
    int t = threadIdx.x;
    int v = (t < NSB) ? bsum[t] : 0;
    ps[t] = v;
    __syncthreads();
    for (int off = 1; off < 256; off <<= 1) {
        int x = (t >= off) ? ps[t - off] : 0;
        __syncthreads();
        ps[t] += x;
        __syncthreads();
    }
    if (t < NSB) bpre[t] = ps[t] - v;   // exclusive block prefix
}

__global__ __launch_bounds__(256) void scan3_kernel(const int* __restrict__ cnt,
                                                    const int* __restrict__ bpre,
                                                    int* __restrict__ offs,
                                                    int* __restrict__ cursor) {
    __shared__ int ps[256];
    int t = threadIdx.x;
    int idx = blockIdx.x * 256 + t;
    int v = (idx < NNODES) ? cnt[idx] : 0;
    ps[t] = v;
    __syncthreads();
    for (int off = 1; off < 256; off <<= 1) {
        int x = (t >= off) ? ps[t - off] : 0;
        __syncthreads();
        ps[t] += x;
        __syncthreads();
    }
    int ex = ps[t] - v + bpre[blockIdx.x];
    if (idx < NNODES) { offs[idx] = ex; cursor[idx] = ex; }
    if (idx == NNODES) offs[NNODES] = NEDGES;
}

__global__ __launch_bounds__(256) void scatter_kernel(const int* __restrict__ row,
                                                      const int* __restrict__ col,
                                                      int* __restrict__ cursor,
                                                      int* __restrict__ rank,
                                                      int* __restrict__ col_perm) {
    int e = blockIdx.x * 256 + threadIdx.x;
    if (e < NEDGES) {
        int pos = atomicAdd(&cursor[row[e]], 1);
        rank[e] = pos;
        col_perm[pos] = col[e];
    }
}

// ---------------------------------------------------------------------------
// ebias[pos,h] = bf16( ef[e,:] . We[:,h] + be[h] )   (CSR order, pos=rank[e])
// ---------------------------------------------------------------------------
__global__ __launch_bounds__(256) void ef_bias_kernel(const float* __restrict__ EF,
                                                      const int* __restrict__ rank,
                                                      const float* __restrict__ We,
                                                      const float* __restrict__ be,
                                                      unsigned short* __restrict__ ebias) {
    __shared__ float sWe[8][128];   // [h][d]
    __shared__ float sbe[8];
    for (int i = threadIdx.x; i < 1024; i += 256) {
        int d = i >> 3, h = i & 7;
        sWe[h][d] = We[i];          // We is [d][h] row-major
    }
    if (threadIdx.x < 8) sbe[threadIdx.x] = be[threadIdx.x];
    __syncthreads();

    int g = blockIdx.x * 256 + threadIdx.x;   // NEDGES*8 threads
    int e = g >> 3;
    int s = g & 7;
    if (e >= NEDGES) return;

    const fvec4* efv = (const fvec4*)(EF + (size_t)e * 128);
    float acc[8] = {0.f, 0.f, 0.f, 0.f, 0.f, 0.f, 0.f, 0.f};
    #pragma unroll
    for (int i = 0; i < 4; ++i) {
        int d4 = s + 8 * i;
        fvec4 v = __builtin_nontemporal_load(&efv[d4]);
        #pragma unroll
        for (int h = 0; h < 8; ++h) {
            fvec4 w = *(const fvec4*)&sWe[h][d4 * 4];
            acc[h] += v.x * w.x + v.y * w.y + v.z * w.z + v.w * w.w;
        }
    }

    #pragma unroll
    for (int off = 1; off < 8; off <<= 1)
        #pragma unroll
        for (int h = 0; h < 8; ++h)
            acc[h] += __shfl_xor(acc[h], off);

    int pos = rank[e];
    ebias[(size_t)pos * 8 + s] = f2bf(acc[s] + sbe[s]);
}

// ---------------------------------------------------------------------------
// fused QK^T + online segment softmax + PV; part-interleaved bf16 KV.
// Per instruction each 8-lane slot-group reads 128B CONTIGUOUS (2 lines):
//   ku0=kp[h] (head h dims0-7), ku1=kp[8+h], vu0=kp[16+h], vu1=kp[24+h]
// ---------------------------------------------------------------------------
__global__ __launch_bounds__(256) void fused_agg(const unsigned short* __restrict__ Qb,
                                                 const unsigned short* __restrict__ KV,
                                                 const unsigned short* __restrict__ ebias,
                                                 const int* __restrict__ col_perm,
                                                 const int* __restrict__ offs,
                                                 unsigned short* __restrict__ aggb) {
    int node = blockIdx.x * 4 + (threadIdx.x >> 6);
    if (node >= NNODES) return;
    int lane = threadIdx.x & 63;
    int slot = lane >> 3;
    int h    = lane & 7;
    int start = offs[node];
    int end   = offs[node + 1];

    const uint4* qp = (const uint4*)(Qb + (size_t)node * 128 + h * 16);
    uint4 qu0 = qp[0], qu1 = qp[1];
    fvec4 q0, q1, q2, q3;
    bf8_to_f32(qu0, q0, q1);
    bf8_to_f32(qu1, q2, q3);

    float m = -3.0e38f;
    float sum = 0.0f;
    fvec4 a0 = {0.f,0.f,0.f,0.f}, a1 = {0.f,0.f,0.f,0.f};
    fvec4 a2 = {0.f,0.f,0.f,0.f}, a3 = {0.f,0.f,0.f,0.f};

    for (int i = start + slot; i < end; i += 8) {
        int c = col_perm[i];
        float eb = __uint_as_float(((unsigned int)ebias[(size_t)i * 8 + h]) << 16);
        const uint4* kp = (const uint4*)(KV + (size_t)c * 256);
        uint4 ku0 = kp[h],      ku1 = kp[8 + h];
        uint4 vu0 = kp[16 + h], vu1 = kp[24 + h];
        fvec4 k0, k1, k2, k3, v0, v1, v2, v3;
        bf8_to_f32(ku0, k0, k1);
        bf8_to_f32(ku1, k2, k3);
        bf8_to_f32(vu0, v0, v1);
        bf8_to_f32(vu1, v2, v3);

        fvec4 d4 = q0 * k0 + q1 * k1 + q2 * k2 + q3 * k3;
        float dot = d4.x + d4.y + d4.z + d4.w;

        float s = dot * QK_SCALE + eb;
        float mn = fmaxf(m, s);
        float corr = __expf(m - mn);
        float w = __expf(s - mn);
        sum = sum * corr + w;
        a0 = a0 * corr + w * v0;
        a1 = a1 * corr + w * v1;
        a2 = a2 * corr + w * v2;
        a3 = a3 * corr + w * v3;
        m = mn;
    }

    #pragma unroll
    for (int off = 8; off < 64; off <<= 1) {
        float mo = __shfl_xor(m, off);
        float so = __shfl_xor(sum, off);
        fvec4 b0, b1, b2, b3;
        b0.x = __shfl_xor(a0.x, off); b0.y = __shfl_xor(a0.y, off);
        b0.z = __shfl_xor(a0.z, off); b0.w = __shfl_xor(a0.w, off);
        b1.x = __shfl_xor(a1.x, off); b1.y = __shfl_xor(a1.y, off);
        b1.z = __shfl_xor(a1.z, off); b1.w = __shfl_xor(a1.w, off);
        b2.x = __shfl_xor(a2.x, off); b2.y = __shfl_xor(a2.y, off);
        b2.z = __shfl_xor(a2.z, off); b2.w = __shfl_xor(a2.w, off);
        b3.x = __shfl_xor(a3.x, off); b3.y = __shfl_xor(a3.y, off);
        b3.z = __shfl_xor(a3.z, off); b3.w = __shfl_xor(a3.w, off);
        float M = fmaxf(m, mo);
        float c1 = __expf(m - M);
        float c2 = __expf(mo - M);
        sum = sum * c1 + so * c2;
        a0 = a0 * c1 + b0 * c2;
        a1 = a1 * c1 + b1 * c2;
        a2 = a2 * c1 + b2 * c2;
        a3 = a3 * c1 + b3 * c2;
        m = M;
    }

    if (slot == 0) {
        float inv = (sum > 0.0f) ? (1.0f / sum) : 0.0f;
        unsigned short* op = aggb + (size_t)node * 128 + h * 16;
        ushort4 s;
        s.x = f2bf(a0.x * inv); s.y = f2bf(a0.y * inv); s.z = f2bf(a0.z * inv); s.w = f2bf(a0.w * inv);
        *(ushort4*)(op + 0) = s;
        s.x = f2bf(a1.x * inv); s.y = f2bf(a1.y * inv); s.z = f2bf(a1.z * inv); s.w = f2bf(a1.w * inv);
        *(ushort4*)(op + 4) = s;
        s.x = f2bf(a2.x * inv); s.y = f2bf(a2.y * inv); s.z = f2bf(a2.z * inv); s.w = f2bf(a2.w * inv);
        *(ushort4*)(op + 8) = s;
        s.x = f2bf(a3.x * inv); s.y = f2bf(a3.y * inv); s.z = f2bf(a3.z * inv); s.w = f2bf(a3.w * inv);
        *(ushort4*)(op + 12) = s;
    }
}

// ---------------------------------------------------------------------------
extern "C" void kernel_launch(void* const* d_in, const int* in_sizes, int n_in,
                              void* d_out, int out_size, void* d_ws, size_t ws_size,
                              hipStream_t stream) {
    const float* node = (const float*)d_in[0];
    const int*   ei   = (const int*)d_in[1];
    const float* ef   = (const float*)d_in[2];
    const float* Wq   = (const float*)d_in[3];
    const float* bq   = (const float*)d_in[4];
    const float* Wk   = (const float*)d_in[5];
    const float* bk   = (const float*)d_in[6];
    const float* Wv   = (const float*)d_in[7];
    const float* bv   = (const float*)d_in[8];
    const float* We   = (const float*)d_in[9];
    const float* be   = (const float*)d_in[10];
    const float* Wo   = (const float*)d_in[11];
    const float* bo   = (const float*)d_in[12];
    float* out = (float*)d_out;

    const int* row = ei;
    const int* col = ei + NEDGES;

    // workspace layout (all 16B-aligned)
    unsigned short* Qb   = (unsigned short*)d_ws;                 // NNODES*128 bf16
    unsigned short* KVb  = Qb  + (size_t)NNODES * 128;            // NNODES*256 bf16 (part-interleaved)
    unsigned short* Xb   = KVb + (size_t)NNODES * 256;            // NNODES*128 bf16
    unsigned short* Wb   = Xb  + (size_t)NNODES * 128;            // 4*16384 bf16
    unsigned short* aggb = Wb  + 4 * 16384;                       // NNODES*128 bf16
    unsigned short* ebb  = aggb + (size_t)NNODES * 128;           // NEDGES*8 bf16 (CSR order)
    int*   cnt      = (int*)(ebb + (size_t)NEDGES * 8);           // NNODES
    int*   offs     = cnt + NNODES;                               // NNODES+1
    int*   cursor   = offs + NNODES + 1;                          // NNODES
    int*   rank     = cursor + NNODES;                            // NEDGES
    int*   col_perm = rank + NEDGES;                              // NEDGES
    int*   bsum     = col_perm + NEDGES;                          // 256
    int*   bpre     = bsum + 256;                                 // 256

    prep_kernel<<<(NNODES * 32 + 4 * 16384 + NNODES + 255) / 256, 256, 0, stream>>>(
        node, Wq, Wk, Wv, Wo, Xb, Wb, cnt);
    hist_kernel<<<(NEDGES + 255) / 256, 256, 0, stream>>>(row, cnt);
    scan1_kernel<<<NSB, 256, 0, stream>>>(cnt, bsum);
    scan2_kernel<<<1, 256, 0, stream>>>(bsum, bpre);
    scan3_kernel<<<NSB, 256, 0, stream>>>(cnt, bpre, offs, cursor);
    scatter_kernel<<<(NEDGES + 255) / 256, 256, 0, stream>>>(row, col, cursor, rank, col_perm);

    dim3 gqkv((NNODES + 63) / 64, 3);
    gemm_qkv<<<gqkv, 256, 0, stream>>>(Xb, Wb, bq, bk, bv, Qb, KVb, NNODES);

    ef_bias_kernel<<<NEDGES * 8 / 256, 256, 0, stream>>>(ef, rank, We, be, ebb);

    fused_agg<<<(NNODES + 3) / 4, 256, 0, stream>>>(Qb, KVb, ebb, col_perm, offs, aggb);

    gemm_out<<<(NNODES + 63) / 64, 256, 0, stream>>>(aggb, Wb + 3 * 16384, bo, out, NNODES);
}

// Round 12
// 310.304 us; speedup vs baseline: 5.6056x; 1.0839x over previous
//
#include <hip/hip_runtime.h>
#include <hip/hip_bf16.h>
#include <math.h>

#define NNODES 50000
#define NEDGES 800000
#define DMODEL 128
#define QK_SCALE 0.25f  // 1/sqrt(16)
#define NSB 196         // scan blocks = ceil(NNODES/256)

typedef float fvec4 __attribute__((ext_vector_type(4)));
typedef short sv8  __attribute__((ext_vector_type(8)));   // 8 bf16 in 4 VGPRs

__device__ __forceinline__ unsigned short f2bf(float f) {
    unsigned int u = __float_as_uint(f);
    unsigned int r = (u + 0x7FFFu + ((u >> 16) & 1u)) >> 16;   // RNE
    return (unsigned short)r;
}

// convert 8 packed bf16 (one uint4) -> two fvec4 (memory order)
__device__ __forceinline__ void bf8_to_f32(uint4 u, fvec4& lo, fvec4& hi) {
    lo.x = __uint_as_float(u.x << 16); lo.y = __uint_as_float(u.x & 0xFFFF0000u);
    lo.z = __uint_as_float(u.y << 16); lo.w = __uint_as_float(u.y & 0xFFFF0000u);
    hi.x = __uint_as_float(u.z << 16); hi.y = __uint_as_float(u.z & 0xFFFF0000u);
    hi.z = __uint_as_float(u.w << 16); hi.w = __uint_as_float(u.w & 0xFFFF0000u);
}

// ---------------------------------------------------------------------------
// prep: X f32 -> Xb bf16; Wq/Wk/Wv/Wo f32 [k][n] -> Wb bf16 TRANSPOSED
// [w][n][k]; also zeroes cnt.
// ---------------------------------------------------------------------------
__global__ __launch_bounds__(256) void prep_kernel(const float* __restrict__ X,
                                                   const float* __restrict__ Wq,
                                                   const float* __restrict__ Wk,
                                                   const float* __restrict__ Wv,
                                                   const float* __restrict__ Wo,
                                                   unsigned short* __restrict__ Xb,
                                                   unsigned short* __restrict__ Wb,
                                                   int* __restrict__ cnt) {
    int i = blockIdx.x * 256 + threadIdx.x;
    if (i < NNODES * 32) {                      // float4 granularity
        float4 v = *(const float4*)&X[(size_t)i * 4];
        ushort4 s;
        s.x = f2bf(v.x); s.y = f2bf(v.y); s.z = f2bf(v.z); s.w = f2bf(v.w);
        *(ushort4*)&Xb[(size_t)i * 4] = s;
    } else {
        int j = i - NNODES * 32;
        if (j < 4 * 16384) {
            int w = j >> 14, rem = j & 16383;
            int n = rem >> 7, k = rem & 127;
            const float* src = (w == 0) ? Wq : (w == 1) ? Wk : (w == 2) ? Wv : Wo;
            Wb[j] = f2bf(src[k * 128 + n]);
        } else {
            int c = j - 4 * 16384;
            if (c < NNODES) cnt[c] = 0;
        }
    }
}

// ---------------------------------------------------------------------------
// QKV projection via bf16 MFMA (blockIdx.y = 0/1/2 -> Q/K/V).
// K/V epilogue writes PART-INTERLEAVED rows:
//   KV[c][256] = [Kp0: h0..h7 x8][Kp1][Vp0][Vp1]
//   elem(col) = coff + ((col&8)<<3) + ((col>>4)<<3) + (col&7)
// ---------------------------------------------------------------------------
__global__ __launch_bounds__(256) void gemm_qkv(const unsigned short* __restrict__ Xb,
                                                const unsigned short* __restrict__ Wb,
                                                const float* __restrict__ bq,
                                                const float* __restrict__ bk,
                                                const float* __restrict__ bv,
                                                unsigned short* __restrict__ Qb,
                                                unsigned short* __restrict__ KVb,
                                                int M) {
    __shared__ unsigned short Als[64 * 128];
    __shared__ unsigned short Bls[128 * 128];
    char* Ac = (char*)Als;
    char* Bc = (char*)Bls;

    int z = blockIdx.y;
    int r0 = blockIdx.x * 64;
    int tid = threadIdx.x;
    int wave = tid >> 6, lane = tid & 63;

    const char* Wsrc = (const char*)(Wb + (size_t)z * 16384);

    #pragma unroll
    for (int p = 0; p < 4; ++p) {
        int o = p * 4096 + tid * 16;
        int r = o >> 8;
        int gr = r0 + r; if (gr >= M) gr = M - 1;
        uint4 v = *(const uint4*)((const char*)Xb + (size_t)gr * 256 + (o & 255));
        *(uint4*)(Ac + r * 256 + ((o & 255) ^ ((r & 7) << 4))) = v;
    }
    #pragma unroll
    for (int p = 0; p < 8; ++p) {
        int o = p * 4096 + tid * 16;
        int r = o >> 8;
        uint4 v = *(const uint4*)(Wsrc + o);
        *(uint4*)(Bc + (o ^ ((r & 7) << 4))) = v;
    }
    __syncthreads();

    fvec4 acc[8] = {};
    int arow = wave * 16 + (lane & 15);
    int kchunk = (lane >> 4) * 16;

    #pragma unroll
    for (int ks = 0; ks < 4; ++ks) {
        int ain = (ks * 64 + kchunk) ^ ((arow & 7) << 4);
        sv8 af = *(const sv8*)(Ac + arow * 256 + ain);
        #pragma unroll
        for (int cf = 0; cf < 8; ++cf) {
            int brow = cf * 16 + (lane & 15);
            int bin = (ks * 64 + kchunk) ^ ((brow & 7) << 4);
            sv8 bf = *(const sv8*)(Bc + brow * 256 + bin);
            acc[cf] = __builtin_amdgcn_mfma_f32_16x16x32_bf16(af, bf, acc[cf], 0, 0, 0);
        }
    }

    const float* bias = (z == 0) ? bq : (z == 1) ? bk : bv;

    #pragma unroll
    for (int cf = 0; cf < 8; ++cf) {
        int col = cf * 16 + (lane & 15);
        float b = bias[col];
        #pragma unroll
        for (int r = 0; r < 4; ++r) {
            int gr = r0 + wave * 16 + ((lane >> 4) * 4) + r;
            if (gr < M) {
                unsigned short val = f2bf(acc[cf][r] + b);
                if (z == 0) {
                    Qb[(size_t)gr * 128 + col] = val;
                } else {
                    int coff = (z == 1) ? 0 : 128;
                    int off = coff + ((col & 8) << 3) + ((col >> 4) << 3) + (col & 7);
                    KVb[(size_t)gr * 256 + off] = val;
                }
            }
        }
    }
}

// ---------------------------------------------------------------------------
// output projection via bf16 MFMA: out f32 = aggb bf16 @ Wo^T bf16 + bo
// ---------------------------------------------------------------------------
__global__ __launch_bounds__(256) void gemm_out(const unsigned short* __restrict__ Ab,
                                                const unsigned short* __restrict__ Wob,
                                                const float* __restrict__ bo,
                                                float* __restrict__ outp, int M) {
    __shared__ unsigned short Als[64 * 128];
    __shared__ unsigned short Bls[128 * 128];
    char* Ac = (char*)Als;
    char* Bc = (char*)Bls;

    int r0 = blockIdx.x * 64;
    int tid = threadIdx.x;
    int wave = tid >> 6, lane = tid & 63;

    #pragma unroll
    for (int p = 0; p < 4; ++p) {
        int o = p * 4096 + tid * 16;
        int r = o >> 8;
        int gr = r0 + r; if (gr >= M) gr = M - 1;
        uint4 v = *(const uint4*)((const char*)Ab + (size_t)gr * 256 + (o & 255));
        *(uint4*)(Ac + r * 256 + ((o & 255) ^ ((r & 7) << 4))) = v;
    }
    #pragma unroll
    for (int p = 0; p < 8; ++p) {
        int o = p * 4096 + tid * 16;
        int r = o >> 8;
        uint4 v = *(const uint4*)((const char*)Wob + o);
        *(uint4*)(Bc + (o ^ ((r & 7) << 4))) = v;
    }
    __syncthreads();

    fvec4 acc[8] = {};
    int arow = wave * 16 + (lane & 15);
    int kchunk = (lane >> 4) * 16;

    #pragma unroll
    for (int ks = 0; ks < 4; ++ks) {
        int ain = (ks * 64 + kchunk) ^ ((arow & 7) << 4);
        sv8 af = *(const sv8*)(Ac + arow * 256 + ain);
        #pragma unroll
        for (int cf = 0; cf < 8; ++cf) {
            int brow = cf * 16 + (lane & 15);
            int bin = (ks * 64 + kchunk) ^ ((brow & 7) << 4);
            sv8 bf = *(const sv8*)(Bc + brow * 256 + bin);
            acc[cf] = __builtin_amdgcn_mfma_f32_16x16x32_bf16(af, bf, acc[cf], 0, 0, 0);
        }
    }

    #pragma unroll
    for (int cf = 0; cf < 8; ++cf) {
        int col = cf * 16 + (lane & 15);
        float b = bo[col];
        #pragma unroll
        for (int r = 0; r < 4; ++r) {
            int gr = r0 + wave * 16 + ((lane >> 4) * 4) + r;
            if (gr < M) outp[(size_t)gr * 128 + col] = acc[cf][r] + b;
        }
    }
}

// ---------------------------------------------------------------------------
// CSR build: histogram -> 3-phase parallel scan (scatter fused into ef_bias)
// ---------------------------------------------------------------------------
__global__ __launch_bounds__(256) void hist_kernel(const int* __restrict__ row,
                                                   int* __restrict__ cnt) {
    int e = blockIdx.x * 256 + threadIdx.x;
    if (e < NEDGES) atomicAdd(&cnt[row[e]], 1);
}

__global__ __launch_bounds__(256) void scan1_kernel(const int* __restrict__ cnt,
                                                    int* __restrict__ bsum) {
    __shared__ int red[256];
    int idx = blockIdx.x * 256 + threadIdx.x;
    red[threadIdx.x] = (idx < NNODES) ? cnt[idx] : 0;
    __syncthreads();
    for (int off = 128; off > 0; off >>= 1) {
        if (threadIdx.x < off) red[threadIdx.x] += red[threadIdx.x + off];
        __syncthreads();
    }
    if (threadIdx.x == 0) bsum[blockIdx.x] = red[0];
}

__global__ __launch_bounds__(256) void scan2_kernel(const int* __restrict__ bsum,
                                                    int* __restrict__ bpre) {
    __shared__ int ps[256];
    int t = threadIdx.x;
    int v = (t < NSB) ? bsum[t] : 0;
    ps[t] = v;
    __syncthreads();
    for (int off = 1; off < 256; off <<= 1) {
        int x = (t >= off) ? ps[t - off] : 0;
        __syncthreads();
        ps[t] += x;
        __syncthreads();
    }
    if (t < NSB) bpre[t] = ps[t] - v;   // exclusive block prefix
}

__global__ __launch_bounds__(256) void scan3_kernel(const int* __restrict__ cnt,
                                                    const int* __restrict__ bpre,
                                                    int* __restrict__ offs,
                                                    int* __restrict__ cursor) {
    __shared__ int ps[256];
    int t = threadIdx.x;
    int idx = blockIdx.x * 256 + t;
    int v = (idx < NNODES) ? cnt[idx] : 0;
    ps[t] = v;
    __syncthreads();
    for (int off = 1; off < 256; off <<= 1) {
        int x = (t >= off) ? ps[t - off] : 0;
        __syncthreads();
        ps[t] += x;
        __syncthreads();
    }
    int ex = ps[t] - v + bpre[blockIdx.x];
    if (idx < NNODES) { offs[idx] = ex; cursor[idx] = ex; }
    if (idx == NNODES) offs[NNODES] = NEDGES;
}

// ---------------------------------------------------------------------------
// FUSED ef-bias + scatter: 8 lanes per edge. Lane s==0 claims the CSR slot
// (atomicAdd on cursor, issued EARLY so latency hides under ef streaming)
// and writes col_perm; pos broadcast via shfl; all 8 lanes write
// ebias[pos*8+s] = bf16( ef[e,:] . We[:,s] + be[s] ).
// ---------------------------------------------------------------------------
__global__ __launch_bounds__(256) void ef_bias_scatter(const float* __restrict__ EF,
                                                       const int* __restrict__ row,
                                                       const int* __restrict__ col,
                                                       int* __restrict__ cursor,
                                                       const float* __restrict__ We,
                                                       const float* __restrict__ be,
                                                       unsigned short* __restrict__ ebias,
                                                       int* __restrict__ col_perm) {
    __shared__ float sWe[8][128];   // [h][d]
    __shared__ float sbe[8];
    for (int i = threadIdx.x; i < 1024; i += 256) {
        int d = i >> 3, h = i & 7;
        sWe[h][d] = We[i];          // We is [d][h] row-major
    }
    if (threadIdx.x < 8) sbe[threadIdx.x] = be[threadIdx.x];
    __syncthreads();

    int g = blockIdx.x * 256 + threadIdx.x;   // NEDGES*8 threads
    int e = g >> 3;
    int s = g & 7;
    if (e >= NEDGES) return;
    int lane = threadIdx.x & 63;

    // claim CSR slot early (latency hides under the ef stream below)
    int pos = 0;
    if (s == 0) {
        int r = row[e];
        pos = atomicAdd(&cursor[r], 1);
        col_perm[pos] = col[e];
    }

    const fvec4* efv = (const fvec4*)(EF + (size_t)e * 128);
    float acc[8] = {0.f, 0.f, 0.f, 0.f, 0.f, 0.f, 0.f, 0.f};
    #pragma unroll
    for (int i = 0; i < 4; ++i) {
        int d4 = s + 8 * i;
        fvec4 v = __builtin_nontemporal_load(&efv[d4]);
        #pragma unroll
        for (int h = 0; h < 8; ++h) {
            fvec4 w = *(const fvec4*)&sWe[h][d4 * 4];
            acc[h] += v.x * w.x + v.y * w.y + v.z * w.z + v.w * w.w;
        }
    }

    #pragma unroll
    for (int off = 1; off < 8; off <<= 1)
        #pragma unroll
        for (int h = 0; h < 8; ++h)
            acc[h] += __shfl_xor(acc[h], off);

    pos = __shfl(pos, lane & ~7);             // broadcast from the group's s==0 lane
    ebias[(size_t)pos * 8 + s] = f2bf(acc[s] + sbe[s]);
}

// ---------------------------------------------------------------------------
// fused QK^T + online segment softmax + PV; part-interleaved bf16 KV.
// Per instruction each 8-lane slot-group reads 128B CONTIGUOUS (2 lines).
// ---------------------------------------------------------------------------
__global__ __launch_bounds__(256) void fused_agg(const unsigned short* __restrict__ Qb,
                                                 const unsigned short* __restrict__ KV,
                                                 const unsigned short* __restrict__ ebias,
                                                 const int* __restrict__ col_perm,
                                                 const int* __restrict__ offs,
                                                 unsigned short* __restrict__ aggb) {
    int node = blockIdx.x * 4 + (threadIdx.x >> 6);
    if (node >= NNODES) return;
    int lane = threadIdx.x & 63;
    int slot = lane >> 3;
    int h    = lane & 7;
    int start = offs[node];
    int end   = offs[node + 1];

    const uint4* qp = (const uint4*)(Qb + (size_t)node * 128 + h * 16);
    uint4 qu0 = qp[0], qu1 = qp[1];
    fvec4 q0, q1, q2, q3;
    bf8_to_f32(qu0, q0, q1);
    bf8_to_f32(qu1, q2, q3);

    float m = -3.0e38f;
    float sum = 0.0f;
    fvec4 a0 = {0.f,0.f,0.f,0.f}, a1 = {0.f,0.f,0.f,0.f};
    fvec4 a2 = {0.f,0.f,0.f,0.f}, a3 = {0.f,0.f,0.f,0.f};

    for (int i = start + slot; i < end; i += 8) {
        int c = col_perm[i];
        float eb = __uint_as_float(((unsigned int)ebias[(size_t)i * 8 + h]) << 16);
        const uint4* kp = (const uint4*)(KV + (size_t)c * 256);
        uint4 ku0 = kp[h],      ku1 = kp[8 + h];
        uint4 vu0 = kp[16 + h], vu1 = kp[24 + h];
        fvec4 k0, k1, k2, k3, v0, v1, v2, v3;
        bf8_to_f32(ku0, k0, k1);
        bf8_to_f32(ku1, k2, k3);
        bf8_to_f32(vu0, v0, v1);
        bf8_to_f32(vu1, v2, v3);

        fvec4 d4 = q0 * k0 + q1 * k1 + q2 * k2 + q3 * k3;
        float dot = d4.x + d4.y + d4.z + d4.w;

        float s = dot * QK_SCALE + eb;
        float mn = fmaxf(m, s);
        float corr = __expf(m - mn);
        float w = __expf(s - mn);
        sum = sum * corr + w;
        a0 = a0 * corr + w * v0;
        a1 = a1 * corr + w * v1;
        a2 = a2 * corr + w * v2;
        a3 = a3 * corr + w * v3;
        m = mn;
    }

    #pragma unroll
    for (int off = 8; off < 64; off <<= 1) {
        float mo = __shfl_xor(m, off);
        float so = __shfl_xor(sum, off);
        fvec4 b0, b1, b2, b3;
        b0.x = __shfl_xor(a0.x, off); b0.y = __shfl_xor(a0.y, off);
        b0.z = __shfl_xor(a0.z, off); b0.w = __shfl_xor(a0.w, off);
        b1.x = __shfl_xor(a1.x, off); b1.y = __shfl_xor(a1.y, off);
        b1.z = __shfl_xor(a1.z, off); b1.w = __shfl_xor(a1.w, off);
        b2.x = __shfl_xor(a2.x, off); b2.y = __shfl_xor(a2.y, off);
        b2.z = __shfl_xor(a2.z, off); b2.w = __shfl_xor(a2.w, off);
        b3.x = __shfl_xor(a3.x, off); b3.y = __shfl_xor(a3.y, off);
        b3.z = __shfl_xor(a3.z, off); b3.w = __shfl_xor(a3.w, off);
        float M = fmaxf(m, mo);
        float c1 = __expf(m - M);
        float c2 = __expf(mo - M);
        sum = sum * c1 + so * c2;
        a0 = a0 * c1 + b0 * c2;
        a1 = a1 * c1 + b1 * c2;
        a2 = a2 * c1 + b2 * c2;
        a3 = a3 * c1 + b3 * c2;
        m = M;
    }

    if (slot == 0) {
        float inv = (sum > 0.0f) ? (1.0f / sum) : 0.0f;
        unsigned short* op = aggb + (size_t)node * 128 + h * 16;
        ushort4 s;
        s.x = f2bf(a0.x * inv); s.y = f2bf(a0.y * inv); s.z = f2bf(a0.z * inv); s.w = f2bf(a0.w * inv);
        *(ushort4*)(op + 0) = s;
        s.x = f2bf(a1.x * inv); s.y = f2bf(a1.y * inv); s.z = f2bf(a1.z * inv); s.w = f2bf(a1.w * inv);
        *(ushort4*)(op + 4) = s;
        s.x = f2bf(a2.x * inv); s.y = f2bf(a2.y * inv); s.z = f2bf(a2.z * inv); s.w = f2bf(a2.w * inv);
        *(ushort4*)(op + 8) = s;
        s.x = f2bf(a3.x * inv); s.y = f2bf(a3.y * inv); s.z = f2bf(a3.z * inv); s.w = f2bf(a3.w * inv);
        *(ushort4*)(op + 12) = s;
    }
}

// ---------------------------------------------------------------------------
extern "C" void kernel_launch(void* const* d_in, const int* in_sizes, int n_in,
                              void* d_out, int out_size, void* d_ws, size_t ws_size,
                              hipStream_t stream) {
    const float* node = (const float*)d_in[0];
    const int*   ei   = (const int*)d_in[1];
    const float* ef   = (const float*)d_in[2];
    const float* Wq   = (const float*)d_in[3];
    const float* bq   = (const float*)d_in[4];
    const float* Wk   = (const float*)d_in[5];
    const float* bk   = (const float*)d_in[6];
    const float* Wv   = (const float*)d_in[7];
    const float* bv   = (const float*)d_in[8];
    const float* We   = (const float*)d_in[9];
    const float* be   = (const float*)d_in[10];
    const float* Wo   = (const float*)d_in[11];
    const float* bo   = (const float*)d_in[12];
    float* out = (float*)d_out;

    const int* row = ei;
    const int* col = ei + NEDGES;

    // workspace layout (all 16B-aligned)
    unsigned short* Qb   = (unsigned short*)d_ws;                 // NNODES*128 bf16
    unsigned short* KVb  = Qb  + (size_t)NNODES * 128;            // NNODES*256 bf16 (part-interleaved)
    unsigned short* Xb   = KVb + (size_t)NNODES * 256;            // NNODES*128 bf16
    unsigned short* Wb   = Xb  + (size_t)NNODES * 128;            // 4*16384 bf16
    unsigned short* aggb = Wb  + 4 * 16384;                       // NNODES*128 bf16
    unsigned short* ebb  = aggb + (size_t)NNODES * 128;           // NEDGES*8 bf16 (CSR order)
    int*   cnt      = (int*)(ebb + (size_t)NEDGES * 8);           // NNODES
    int*   offs     = cnt + NNODES;                               // NNODES+1
    int*   cursor   = offs + NNODES + 1;                          // NNODES
    int*   col_perm = cursor + NNODES;                            // NEDGES
    int*   bsum     = col_perm + NEDGES;                          // 256
    int*   bpre     = bsum + 256;                                 // 256

    prep_kernel<<<(NNODES * 32 + 4 * 16384 + NNODES + 255) / 256, 256, 0, stream>>>(
        node, Wq, Wk, Wv, Wo, Xb, Wb, cnt);
    hist_kernel<<<(NEDGES + 255) / 256, 256, 0, stream>>>(row, cnt);
    scan1_kernel<<<NSB, 256, 0, stream>>>(cnt, bsum);
    scan2_kernel<<<1, 256, 0, stream>>>(bsum, bpre);
    scan3_kernel<<<NSB, 256, 0, stream>>>(cnt, bpre, offs, cursor);

    dim3 gqkv((NNODES + 63) / 64, 3);
    gemm_qkv<<<gqkv, 256, 0, stream>>>(Xb, Wb, bq, bk, bv, Qb, KVb, NNODES);

    ef_bias_scatter<<<NEDGES * 8 / 256, 256, 0, stream>>>(ef, row, col, cursor, We, be, ebb, col_perm);

    fused_agg<<<(NNODES + 3) / 4, 256, 0, stream>>>(Qb, KVb, ebb, col_perm, offs, aggb);

    gemm_out<<<(NNODES + 63) / 64, 256, 0, stream>>>(aggb, Wb + 3 * 16384, bo, out, NNODES);
}